// Round 1
// baseline (849.454 us; speedup 1.0000x reference)
//
#include <hip/hip_runtime.h>
#include <hip/hip_bf16.h>
#include <stdint.h>

using bf16 = __hip_bfloat16;
typedef __attribute__((ext_vector_type(8))) short short8;
typedef __attribute__((ext_vector_type(4))) float f32x4;

#define MFMA16(a,b,c) __builtin_amdgcn_mfma_f32_16x16x32_bf16(a,b,c,0,0,0)

__device__ __forceinline__ void gload_lds16(const void* g, void* l) {
  __builtin_amdgcn_global_load_lds((const __attribute__((address_space(1))) void*)g,
                                   (__attribute__((address_space(3))) void*)l, 16, 0, 0);
}

__device__ __forceinline__ short bf_bits(float f) {
  bf16 h = __float2bfloat16(f);
  return *reinterpret_cast<short*>(&h);
}

// ---------------- f32 -> bf16 elementwise (8/thread) ----------------
__global__ __launch_bounds__(256) void f32_to_bf16_k(const float* __restrict__ in,
                                                     bf16* __restrict__ out, size_t n) {
  size_t i = ((size_t)blockIdx.x * 256 + threadIdx.x) * 8;
  if (i >= n) return;
  float4 a = *(const float4*)(in + i);
  float4 b = *(const float4*)(in + i + 4);
  short8 pk;
  pk[0] = bf_bits(a.x); pk[1] = bf_bits(a.y); pk[2] = bf_bits(a.z); pk[3] = bf_bits(a.w);
  pk[4] = bf_bits(b.x); pk[5] = bf_bits(b.y); pk[6] = bf_bits(b.z); pk[7] = bf_bits(b.w);
  *(short8*)(out + i) = pk;
}

// ---------------- transpose + convert: in[K][N] f32 -> out[N][K] bf16 ----------------
__global__ __launch_bounds__(256) void transpose_cvt_k(const float* __restrict__ in,
                                                       bf16* __restrict__ out, int K, int N) {
  __shared__ float tile[32][33];
  int n0 = blockIdx.x * 32, k0 = blockIdx.y * 32;
  int tx = threadIdx.x & 31, ty = threadIdx.x >> 5;  // 32 x 8
#pragma unroll
  for (int j = 0; j < 4; ++j) {
    int kk = ty + j * 8;
    tile[kk][tx] = in[(size_t)(k0 + kk) * N + n0 + tx];
  }
  __syncthreads();
#pragma unroll
  for (int j = 0; j < 4; ++j) {
    int nn = ty + j * 8;
    out[(size_t)(n0 + nn) * K + k0 + tx] = __float2bfloat16(tile[tx][nn]);
  }
}

// ---------------- V transpose: v[(b*T+t)][kv*128+d] -> vt[((b*4+kv)*128+d)][t] ----------------
__global__ __launch_bounds__(256) void transpose_v_k(const bf16* __restrict__ v,
                                                     bf16* __restrict__ vt) {
  constexpr int T = 2048, Dh = 128, KV = 4;
  __shared__ bf16 tile[32][33];
  int t0 = blockIdx.x * 32, d0 = blockIdx.y * 32;
  int b = blockIdx.z >> 2, kv = blockIdx.z & 3;
  int tx = threadIdx.x & 31, ty = threadIdx.x >> 5;
#pragma unroll
  for (int j = 0; j < 4; ++j) {
    int tt = ty + j * 8;
    tile[tt][tx] = v[((size_t)(b * T + t0 + tt)) * (KV * Dh) + kv * Dh + d0 + tx];
  }
  __syncthreads();
#pragma unroll
  for (int j = 0; j < 4; ++j) {
    int dd = ty + j * 8;
    vt[((size_t)((b * KV + kv) * Dh + d0 + dd)) * T + t0 + tx] = tile[tx][dd];
  }
}

// ---------------- fused RoPE + RMSNorm (in place), 1 wave per (token,head) row ----------------
__global__ __launch_bounds__(256) void rope_rms_k(bf16* __restrict__ buf,
                                                  const float* __restrict__ cosp,
                                                  const float* __restrict__ sinp,
                                                  int nh, float outscale) {
  constexpr int T = 2048;
  int wid = blockIdx.x * 4 + (threadIdx.x >> 6);
  int lane = threadIdx.x & 63;
  int h = wid % nh;
  int tok = wid / nh;          // b*T + t
  int t = tok & (T - 1);
  bf16* p = buf + (size_t)tok * (nh * 128) + h * 128;
  float x1 = __bfloat162float(p[lane]);
  float x2 = __bfloat162float(p[lane + 64]);
  float c = cosp[t * 64 + lane], s = sinp[t * 64 + lane];
  float o1 = x1 * c - x2 * s;
  float o2 = x1 * s + x2 * c;
  float ss = o1 * o1 + o2 * o2;
#pragma unroll
  for (int m = 1; m < 64; m <<= 1) ss += __shfl_xor(ss, m, 64);
  float r = rsqrtf(ss * (1.f / 128.f) + 1e-5f) * outscale;
  p[lane] = __float2bfloat16(o1 * r);
  p[lane + 64] = __float2bfloat16(o2 * r);
}

// ---------------- bf16 GEMM: C[M][N] = A[M][K] * Bt[N][K]^T  (m97 structure) ----------------
__device__ __forceinline__ void store_c(float* C, size_t i, float v) { C[i] = v; }
__device__ __forceinline__ void store_c(bf16* C, size_t i, float v) { C[i] = __float2bfloat16(v); }

template <typename OutT>
__global__ __launch_bounds__(256) void gemm_bt(const bf16* __restrict__ A,
                                               const bf16* __restrict__ Bt,
                                               OutT* __restrict__ C, int M, int N, int K) {
  constexpr int BM = 128, BN = 128, BK = 64;
  __shared__ bf16 sA[BM * BK];
  __shared__ bf16 sB[BN * BK];
  int tid = threadIdx.x;
  int lane = tid & 63, w = tid >> 6;
  int m0 = blockIdx.x * BM, n0 = blockIdx.y * BN;
  int wm = (w >> 1) * 64, wn = (w & 1) * 64;
  f32x4 acc[4][4] = {};
  int nk = K / BK;
  for (int kt = 0; kt < nk; ++kt) {
    __syncthreads();
    int kb = kt * BK;
#pragma unroll
    for (int it = 0; it < 4; ++it) {
      int off = tid * 16 + it * 4096;
      int row = off >> 7, cb = off & 127;
      gload_lds16((const char*)A + (((size_t)(m0 + row)) * K + kb) * 2 + cb, (char*)sA + off);
    }
#pragma unroll
    for (int it = 0; it < 4; ++it) {
      int off = tid * 16 + it * 4096;
      int row = off >> 7, cb = off & 127;
      gload_lds16((const char*)Bt + (((size_t)(n0 + row)) * K + kb) * 2 + cb, (char*)sB + off);
    }
    asm volatile("s_waitcnt vmcnt(0)" ::: "memory");
    __syncthreads();
#pragma unroll
    for (int ks = 0; ks < 2; ++ks) {
      short8 af[4], bfr[4];
#pragma unroll
      for (int i = 0; i < 4; ++i) {
        af[i]  = *(const short8*)(sA + (wm + i * 16 + (lane & 15)) * BK + ks * 32 + (lane >> 4) * 8);
        bfr[i] = *(const short8*)(sB + (wn + i * 16 + (lane & 15)) * BK + ks * 32 + (lane >> 4) * 8);
      }
#pragma unroll
      for (int i = 0; i < 4; ++i)
#pragma unroll
        for (int j = 0; j < 4; ++j)
          acc[i][j] = MFMA16(af[i], bfr[j], acc[i][j]);
    }
  }
#pragma unroll
  for (int i = 0; i < 4; ++i) {
    int row = m0 + wm + i * 16 + (lane >> 4) * 4;
#pragma unroll
    for (int j = 0; j < 4; ++j) {
      int col = n0 + wn + j * 16 + (lane & 15);
#pragma unroll
      for (int r = 0; r < 4; ++r)
        store_c(C, (size_t)(row + r) * N + col, acc[i][j][r]);
    }
  }
}

// ---------------- flash attention: q[(b*T+t)][h*128+d], k[(b*T+t)][kv*128+d], vt[((b*4+kv)*128+d)][t] ----------------
__global__ __launch_bounds__(512) void attn_k(const bf16* __restrict__ q,
                                              const bf16* __restrict__ k,
                                              const bf16* __restrict__ vt,
                                              bf16* __restrict__ y) {
  constexpr int T = 2048, Dh = 128, H = 16, KV = 4, QB = 128, KB = 64, NW = 8;
  __shared__ bf16 sK[KB * Dh];      // [kv][d]
  __shared__ bf16 sV[Dh * KB];      // [d][kv]
  __shared__ bf16 sP[NW * 16 * KB]; // per-wave 16x64
  int tid = threadIdx.x, lane = tid & 63, w = tid >> 6;
  int bx = blockIdx.x;
  int qt = bx & 15, h = (bx >> 4) & 15, b = bx >> 8;
  int kh = h >> 2;
  int qrow0 = qt * QB + w * 16;
  short8 aq[4];
  {
    int t0 = qrow0 + (lane & 15);
    const bf16* qp = q + ((size_t)(b * T + t0)) * (H * Dh) + h * Dh + (lane >> 4) * 8;
#pragma unroll
    for (int ks = 0; ks < 4; ++ks) aq[ks] = *(const short8*)(qp + ks * 32);
  }
  f32x4 acc_o[8];
#pragma unroll
  for (int i = 0; i < 8; ++i) acc_o[i] = (f32x4){0.f, 0.f, 0.f, 0.f};
  float mrow[4], lrow[4];
#pragma unroll
  for (int r = 0; r < 4; ++r) { mrow[r] = -INFINITY; lrow[r] = 0.f; }
  int nt = qt * 2 + 2;
  for (int it = 0; it < nt; ++it) {
    int kv0 = it * KB;
    __syncthreads();
#pragma unroll
    for (int p = 0; p < 2; ++p) {  // stage K tile: 64 rows x 256B
      int off = tid * 16 + p * 8192;
      int row = off >> 8, cb = off & 255;
      gload_lds16((const char*)k + (((size_t)(b * T + kv0 + row)) * (KV * Dh) + kh * Dh) * 2 + cb,
                  (char*)sK + off);
    }
#pragma unroll
    for (int p = 0; p < 2; ++p) {  // stage Vt tile: 128 rows x 128B
      int off = tid * 16 + p * 8192;
      int row = off >> 7, cb = off & 127;
      gload_lds16((const char*)vt + (((size_t)((b * KV + kh) * Dh + row)) * T + kv0) * 2 + cb,
                  (char*)sV + off);
    }
    asm volatile("s_waitcnt vmcnt(0)" ::: "memory");
    __syncthreads();
    f32x4 s[4];
#pragma unroll
    for (int c = 0; c < 4; ++c) s[c] = (f32x4){0.f, 0.f, 0.f, 0.f};
#pragma unroll
    for (int ks = 0; ks < 4; ++ks) {
#pragma unroll
      for (int c = 0; c < 4; ++c) {
        short8 bk = *(const short8*)(sK + (c * 16 + (lane & 15)) * Dh + ks * 32 + (lane >> 4) * 8);
        s[c] = MFMA16(aq[ks], bk, s[c]);
      }
    }
    if (it >= nt - 2) {  // causal mask (only the 2 diagonal tiles need it)
#pragma unroll
      for (int c = 0; c < 4; ++c) {
        int kvg = kv0 + c * 16 + (lane & 15);
#pragma unroll
        for (int r = 0; r < 4; ++r) {
          int qg = qrow0 + (lane >> 4) * 4 + r;
          if (kvg > qg) s[c][r] = -INFINITY;
        }
      }
    }
    float pv[4][4];
#pragma unroll
    for (int r = 0; r < 4; ++r) {
      float mt = fmaxf(fmaxf(s[0][r], s[1][r]), fmaxf(s[2][r], s[3][r]));
#pragma unroll
      for (int m = 1; m < 16; m <<= 1) mt = fmaxf(mt, __shfl_xor(mt, m, 64));
      float mn = fmaxf(mrow[r], mt);
      float corr = __expf(mrow[r] - mn);
      mrow[r] = mn;
      float rsum = 0.f;
#pragma unroll
      for (int c = 0; c < 4; ++c) { float e = __expf(s[c][r] - mn); pv[c][r] = e; rsum += e; }
#pragma unroll
      for (int m = 1; m < 16; m <<= 1) rsum += __shfl_xor(rsum, m, 64);
      lrow[r] = lrow[r] * corr + rsum;
#pragma unroll
      for (int dc = 0; dc < 8; ++dc) acc_o[dc][r] *= corr;
    }
    bf16* myP = sP + w * 16 * KB;
#pragma unroll
    for (int c = 0; c < 4; ++c)
#pragma unroll
      for (int r = 0; r < 4; ++r)
        myP[((lane >> 4) * 4 + r) * KB + c * 16 + (lane & 15)] = __float2bfloat16(pv[c][r]);
#pragma unroll
    for (int ks = 0; ks < 2; ++ks) {
      short8 pa = *(const short8*)(myP + (lane & 15) * KB + ks * 32 + (lane >> 4) * 8);
#pragma unroll
      for (int dc = 0; dc < 8; ++dc) {
        short8 bv = *(const short8*)(sV + (dc * 16 + (lane & 15)) * KB + ks * 32 + (lane >> 4) * 8);
        acc_o[dc] = MFMA16(pa, bv, acc_o[dc]);
      }
    }
  }
#pragma unroll
  for (int r = 0; r < 4; ++r) {
    float inv = 1.f / lrow[r];
    int tg = qrow0 + (lane >> 4) * 4 + r;
    bf16* yp = y + ((size_t)(b * T + tg)) * (H * Dh) + h * Dh + (lane & 15);
#pragma unroll
    for (int dc = 0; dc < 8; ++dc)
      yp[dc * 16] = __float2bfloat16(acc_o[dc][r] * inv);
  }
}

// ---------------- launch ----------------
extern "C" void kernel_launch(void* const* d_in, const int* in_sizes, int n_in,
                              void* d_out, int out_size, void* d_ws, size_t ws_size,
                              hipStream_t stream) {
  const float* x    = (const float*)d_in[0];
  const float* cosp = (const float*)d_in[1];
  const float* sinp = (const float*)d_in[2];
  const float* wq   = (const float*)d_in[3];
  const float* wk   = (const float*)d_in[4];
  const float* wv   = (const float*)d_in[5];
  const float* wp   = (const float*)d_in[6];
  float* out = (float*)d_out;

  constexpr size_t Mtok = 8192;  // B*T
  constexpr int Cdim = 2048, HD = 2048, KVD = 512;

  char* ws = (char*)d_ws;
  bf16* xb  = (bf16*)ws; ws += Mtok * Cdim * 2;
  bf16* wqT = (bf16*)ws; ws += (size_t)HD * Cdim * 2;
  bf16* wkT = (bf16*)ws; ws += (size_t)KVD * Cdim * 2;
  bf16* wvT = (bf16*)ws; ws += (size_t)KVD * Cdim * 2;
  bf16* wpT = (bf16*)ws; ws += (size_t)Cdim * HD * 2;
  bf16* qb  = (bf16*)ws; ws += Mtok * HD * 2;
  bf16* kb  = (bf16*)ws; ws += Mtok * KVD * 2;
  bf16* vb  = (bf16*)ws; ws += Mtok * KVD * 2;
  bf16* vtb = (bf16*)ws; ws += Mtok * KVD * 2;
  bf16* yb  = (bf16*)ws; ws += Mtok * HD * 2;

  f32_to_bf16_k<<<dim3(Mtok * Cdim / 8 / 256), 256, 0, stream>>>(x, xb, Mtok * Cdim);
  transpose_cvt_k<<<dim3(HD / 32, Cdim / 32), 256, 0, stream>>>(wq, wqT, Cdim, HD);
  transpose_cvt_k<<<dim3(KVD / 32, Cdim / 32), 256, 0, stream>>>(wk, wkT, Cdim, KVD);
  transpose_cvt_k<<<dim3(KVD / 32, Cdim / 32), 256, 0, stream>>>(wv, wvT, Cdim, KVD);
  transpose_cvt_k<<<dim3(Cdim / 32, HD / 32), 256, 0, stream>>>(wp, wpT, HD, Cdim);

  gemm_bt<bf16><<<dim3(64, 16), 256, 0, stream>>>(xb, wqT, qb, (int)Mtok, HD, Cdim);
  gemm_bt<bf16><<<dim3(64, 4), 256, 0, stream>>>(xb, wkT, kb, (int)Mtok, KVD, Cdim);
  gemm_bt<bf16><<<dim3(64, 4), 256, 0, stream>>>(xb, wvT, vb, (int)Mtok, KVD, Cdim);

  rope_rms_k<<<dim3(Mtok * 16 / 4), 256, 0, stream>>>(qb, cosp, sinp, 16, 0.08838834764831845f);
  rope_rms_k<<<dim3(Mtok * 4 / 4), 256, 0, stream>>>(kb, cosp, sinp, 4, 1.0f);
  transpose_v_k<<<dim3(64, 4, 16), 256, 0, stream>>>(vb, vtb);

  attn_k<<<dim3(1024), 512, 0, stream>>>(qb, kb, vtb, yb);

  gemm_bt<float><<<dim3(64, 16), 256, 0, stream>>>(yb, wpT, out, (int)Mtok, HD, Cdim);
}

// Round 2
// 535.813 us; speedup vs baseline: 1.5854x; 1.5854x over previous
//
#include <hip/hip_runtime.h>
#include <hip/hip_bf16.h>
#include <stdint.h>

using bf16 = __hip_bfloat16;
typedef __attribute__((ext_vector_type(8))) short short8;
typedef __attribute__((ext_vector_type(4))) float f32x4;

#define MFMA16(a,b,c) __builtin_amdgcn_mfma_f32_16x16x32_bf16(a,b,c,0,0,0)

__device__ __forceinline__ void gload_lds16(const void* g, void* l) {
  __builtin_amdgcn_global_load_lds((const __attribute__((address_space(1))) void*)g,
                                   (__attribute__((address_space(3))) void*)l, 16, 0, 0);
}

__device__ __forceinline__ short bf_bits(float f) {
  bf16 h = __float2bfloat16(f);
  return *reinterpret_cast<short*>(&h);
}

// ---------------- f32 -> bf16 elementwise (8/thread) ----------------
__global__ __launch_bounds__(256) void f32_to_bf16_k(const float* __restrict__ in,
                                                     bf16* __restrict__ out, size_t n) {
  size_t i = ((size_t)blockIdx.x * 256 + threadIdx.x) * 8;
  if (i >= n) return;
  float4 a = *(const float4*)(in + i);
  float4 b = *(const float4*)(in + i + 4);
  short8 pk;
  pk[0] = bf_bits(a.x); pk[1] = bf_bits(a.y); pk[2] = bf_bits(a.z); pk[3] = bf_bits(a.w);
  pk[4] = bf_bits(b.x); pk[5] = bf_bits(b.y); pk[6] = bf_bits(b.z); pk[7] = bf_bits(b.w);
  *(short8*)(out + i) = pk;
}

// ---------------- transpose + convert: in[K][N] f32 -> out[N][K] bf16 ----------------
__global__ __launch_bounds__(256) void transpose_cvt_k(const float* __restrict__ in,
                                                       bf16* __restrict__ out, int K, int N) {
  __shared__ float tile[32][33];
  int n0 = blockIdx.x * 32, k0 = blockIdx.y * 32;
  int tx = threadIdx.x & 31, ty = threadIdx.x >> 5;  // 32 x 8
#pragma unroll
  for (int j = 0; j < 4; ++j) {
    int kk = ty + j * 8;
    tile[kk][tx] = in[(size_t)(k0 + kk) * N + n0 + tx];
  }
  __syncthreads();
#pragma unroll
  for (int j = 0; j < 4; ++j) {
    int nn = ty + j * 8;
    out[(size_t)(n0 + nn) * K + k0 + tx] = __float2bfloat16(tile[tx][nn]);
  }
}

// ---------------- V transpose: v[(b*T+t)][kv*128+d] -> vt[((b*4+kv)*128+d)][t] ----------------
__global__ __launch_bounds__(256) void transpose_v_k(const bf16* __restrict__ v,
                                                     bf16* __restrict__ vt) {
  constexpr int T = 2048, Dh = 128, KV = 4;
  __shared__ bf16 tile[32][33];
  int t0 = blockIdx.x * 32, d0 = blockIdx.y * 32;
  int b = blockIdx.z >> 2, kv = blockIdx.z & 3;
  int tx = threadIdx.x & 31, ty = threadIdx.x >> 5;
#pragma unroll
  for (int j = 0; j < 4; ++j) {
    int tt = ty + j * 8;
    tile[tt][tx] = v[((size_t)(b * T + t0 + tt)) * (KV * Dh) + kv * Dh + d0 + tx];
  }
  __syncthreads();
#pragma unroll
  for (int j = 0; j < 4; ++j) {
    int dd = ty + j * 8;
    vt[((size_t)((b * KV + kv) * Dh + d0 + dd)) * T + t0 + tx] = tile[tx][dd];
  }
}

// ---------------- fused RoPE + RMSNorm (in place), 1 wave per (token,head) row ----------------
__global__ __launch_bounds__(256) void rope_rms_k(bf16* __restrict__ buf,
                                                  const float* __restrict__ cosp,
                                                  const float* __restrict__ sinp,
                                                  int nh, float outscale) {
  constexpr int T = 2048;
  int wid = blockIdx.x * 4 + (threadIdx.x >> 6);
  int lane = threadIdx.x & 63;
  int h = wid % nh;
  int tok = wid / nh;          // b*T + t
  int t = tok & (T - 1);
  bf16* p = buf + (size_t)tok * (nh * 128) + h * 128;
  float x1 = __bfloat162float(p[lane]);
  float x2 = __bfloat162float(p[lane + 64]);
  float c = cosp[t * 64 + lane], s = sinp[t * 64 + lane];
  float o1 = x1 * c - x2 * s;
  float o2 = x1 * s + x2 * c;
  float ss = o1 * o1 + o2 * o2;
#pragma unroll
  for (int m = 1; m < 64; m <<= 1) ss += __shfl_xor(ss, m, 64);
  float r = rsqrtf(ss * (1.f / 128.f) + 1e-5f) * outscale;
  p[lane] = __float2bfloat16(o1 * r);
  p[lane + 64] = __float2bfloat16(o2 * r);
}

// ---------------- bf16 GEMM: C[M][N] = A[M][K] * Bt[N][K]^T  (m97 structure) ----------------
__device__ __forceinline__ void store_c(float* C, size_t i, float v) { C[i] = v; }
__device__ __forceinline__ void store_c(bf16* C, size_t i, float v) { C[i] = __float2bfloat16(v); }

template <typename OutT>
__global__ __launch_bounds__(256) void gemm_bt(const bf16* __restrict__ A,
                                               const bf16* __restrict__ Bt,
                                               OutT* __restrict__ C, int M, int N, int K) {
  constexpr int BM = 128, BN = 128, BK = 64;
  __shared__ bf16 sA[BM * BK];
  __shared__ bf16 sB[BN * BK];
  int tid = threadIdx.x;
  int lane = tid & 63, w = tid >> 6;
  int m0 = blockIdx.x * BM, n0 = blockIdx.y * BN;
  int wm = (w >> 1) * 64, wn = (w & 1) * 64;
  f32x4 acc[4][4] = {};
  int nk = K / BK;
  for (int kt = 0; kt < nk; ++kt) {
    __syncthreads();
    int kb = kt * BK;
#pragma unroll
    for (int it = 0; it < 4; ++it) {
      int off = tid * 16 + it * 4096;
      int row = off >> 7, cb = off & 127;
      gload_lds16((const char*)A + (((size_t)(m0 + row)) * K + kb) * 2 + cb, (char*)sA + off);
    }
#pragma unroll
    for (int it = 0; it < 4; ++it) {
      int off = tid * 16 + it * 4096;
      int row = off >> 7, cb = off & 127;
      gload_lds16((const char*)Bt + (((size_t)(n0 + row)) * K + kb) * 2 + cb, (char*)sB + off);
    }
    asm volatile("s_waitcnt vmcnt(0)" ::: "memory");
    __syncthreads();
#pragma unroll
    for (int ks = 0; ks < 2; ++ks) {
      short8 af[4], bfr[4];
#pragma unroll
      for (int i = 0; i < 4; ++i) {
        af[i]  = *(const short8*)(sA + (wm + i * 16 + (lane & 15)) * BK + ks * 32 + (lane >> 4) * 8);
        bfr[i] = *(const short8*)(sB + (wn + i * 16 + (lane & 15)) * BK + ks * 32 + (lane >> 4) * 8);
      }
#pragma unroll
      for (int i = 0; i < 4; ++i)
#pragma unroll
        for (int j = 0; j < 4; ++j)
          acc[i][j] = MFMA16(af[i], bfr[j], acc[i][j]);
    }
  }
#pragma unroll
  for (int i = 0; i < 4; ++i) {
    int row = m0 + wm + i * 16 + (lane >> 4) * 4;
#pragma unroll
    for (int j = 0; j < 4; ++j) {
      int col = n0 + wn + j * 16 + (lane & 15);
#pragma unroll
      for (int r = 0; r < 4; ++r)
        store_c(C, (size_t)(row + r) * N + col, acc[i][j][r]);
    }
  }
}

// ---------------- flash attention (swizzled LDS, double-buffered K/V) ----------------
// q[(b*T+t)][h*128+d], k[(b*T+t)][kv*128+d], vt[((b*4+kv)*128+d)][t]
__global__ __launch_bounds__(512) void attn_k(const bf16* __restrict__ q,
                                              const bf16* __restrict__ k,
                                              const bf16* __restrict__ vt,
                                              bf16* __restrict__ y) {
  constexpr int T = 2048, Dh = 128, H = 16, KV = 4, QB = 128, KB = 64;
  // sK: 2 x [64 rows x 256B], sV: 2 x [128 rows x 128B], sP: 8 waves x [16 x 128B]
  __shared__ bf16 sK[2 * 64 * 128];
  __shared__ bf16 sV[2 * 128 * 64];
  __shared__ bf16 sP[8 * 16 * 64];
  int tid = threadIdx.x, lane = tid & 63, w = tid >> 6;
  int bx = blockIdx.x;
  // qt slowest-varying, DESCENDING: longest (diagonal-heavy) blocks dispatch first.
  int qt = 15 - (bx >> 6);
  int b = (bx >> 4) & 3, h = bx & 15;
  int kh = h >> 2;
  int qrow0 = qt * QB + w * 16;
  const int sw = (lane & 7) << 4;          // XOR swizzle for this lane's row group
  const int cb0 = (lane >> 4) << 4;        // 16B sub-column per lane quad

  short8 aq[4];
  {
    int t0 = qrow0 + (lane & 15);
    const bf16* qp = q + ((size_t)(b * T + t0)) * (H * Dh) + h * Dh + (lane >> 4) * 8;
#pragma unroll
    for (int ks = 0; ks < 4; ++ks) aq[ks] = *(const short8*)(qp + ks * 32);
  }
  __builtin_amdgcn_s_waitcnt(0);  // drain Q loads so loop-body waits never touch them

  f32x4 acc_o[8];
#pragma unroll
  for (int i = 0; i < 8; ++i) acc_o[i] = (f32x4){0.f, 0.f, 0.f, 0.f};
  float mrow[4], lrow[4];
#pragma unroll
  for (int r = 0; r < 4; ++r) { mrow[r] = -INFINITY; lrow[r] = 0.f; }

  // stage K/V tile for kv0 into buffer `buf` (linear LDS dest, swizzled global src)
  auto stage = [&](int buf, int kv0) {
#pragma unroll
    for (int p = 0; p < 2; ++p) {  // K: 64 rows x 256B
      int off = tid * 16 + p * 8192;
      int row = off >> 8, cb = off & 255;
      int scb = cb ^ ((row & 7) << 4);
      gload_lds16((const char*)k + (((size_t)(b * T + kv0 + row)) * (KV * Dh) + kh * Dh) * 2 + scb,
                  (char*)sK + buf * 16384 + off);
    }
#pragma unroll
    for (int p = 0; p < 2; ++p) {  // Vt: 128 rows x 128B
      int off = tid * 16 + p * 8192;
      int row = off >> 7, cb = off & 127;
      int scb = cb ^ ((row & 7) << 4);
      gload_lds16((const char*)vt + (((size_t)((b * KV + kh) * Dh + row)) * T + kv0) * 2 + scb,
                  (char*)sV + buf * 16384 + off);
    }
  };

  int nt = qt * 2 + 2;
  stage(0, 0);
  char* myP = (char*)sP + w * 2048;

  for (int it = 0; it < nt; ++it) {
    int cur = it & 1;
    if (it + 1 < nt) {
      stage(cur ^ 1, (it + 1) * KB);
      asm volatile("s_waitcnt vmcnt(4)" ::: "memory");  // current tile done, prefetch in flight
    } else {
      asm volatile("s_waitcnt vmcnt(0)" ::: "memory");
    }
    __builtin_amdgcn_s_barrier();
    const char* sKc = (const char*)sK + cur * 16384;
    const char* sVc = (const char*)sV + cur * 16384;

    // ---- QK^T ----
    f32x4 s[4];
#pragma unroll
    for (int c = 0; c < 4; ++c) s[c] = (f32x4){0.f, 0.f, 0.f, 0.f};
    __builtin_amdgcn_s_setprio(1);
#pragma unroll
    for (int ks = 0; ks < 4; ++ks) {
#pragma unroll
      for (int c = 0; c < 4; ++c) {
        short8 bk = *(const short8*)(sKc + ((c * 16 + (lane & 15)) << 8) + ((ks * 64 + cb0) ^ sw));
        s[c] = MFMA16(aq[ks], bk, s[c]);
      }
    }
    __builtin_amdgcn_s_setprio(0);

    int kv0 = it * KB;
    if (it >= nt - 2) {  // causal mask (only the 2 diagonal tiles need it)
#pragma unroll
      for (int c = 0; c < 4; ++c) {
        int kvg = kv0 + c * 16 + (lane & 15);
#pragma unroll
        for (int r = 0; r < 4; ++r) {
          int qg = qrow0 + (lane >> 4) * 4 + r;
          if (kvg > qg) s[c][r] = -INFINITY;
        }
      }
    }

    // ---- online softmax (wave-parallel, 16-lane groups) ----
    float pv[4][4];
#pragma unroll
    for (int r = 0; r < 4; ++r) {
      float mt = fmaxf(fmaxf(s[0][r], s[1][r]), fmaxf(s[2][r], s[3][r]));
#pragma unroll
      for (int m = 1; m < 16; m <<= 1) mt = fmaxf(mt, __shfl_xor(mt, m, 64));
      float mn = fmaxf(mrow[r], mt);
      float corr = __expf(mrow[r] - mn);
      mrow[r] = mn;
      float rsum = 0.f;
#pragma unroll
      for (int c = 0; c < 4; ++c) { float e = __expf(s[c][r] - mn); pv[c][r] = e; rsum += e; }
#pragma unroll
      for (int m = 1; m < 16; m <<= 1) rsum += __shfl_xor(rsum, m, 64);
      lrow[r] = lrow[r] * corr + rsum;
#pragma unroll
      for (int dc = 0; dc < 8; ++dc) acc_o[dc][r] *= corr;
    }

    // ---- P -> LDS (swizzled write), reload as A-fragment ----
#pragma unroll
    for (int c = 0; c < 4; ++c)
#pragma unroll
      for (int r = 0; r < 4; ++r) {
        int prow = ((lane >> 4) << 2) + r;
        *(bf16*)(myP + (prow << 7) + ((((c * 16 + (lane & 15)) << 1)) ^ ((prow & 7) << 4))) =
            __float2bfloat16(pv[c][r]);
      }

    // ---- PV ----
    __builtin_amdgcn_s_setprio(1);
#pragma unroll
    for (int ks = 0; ks < 2; ++ks) {
      short8 pa = *(const short8*)(myP + ((lane & 15) << 7) + ((ks * 64 + cb0) ^ sw));
#pragma unroll
      for (int dc = 0; dc < 8; ++dc) {
        short8 bv = *(const short8*)(sVc + ((dc * 16 + (lane & 15)) << 7) + ((ks * 64 + cb0) ^ sw));
        acc_o[dc] = MFMA16(pa, bv, acc_o[dc]);
      }
    }
    __builtin_amdgcn_s_setprio(0);
    __builtin_amdgcn_s_barrier();  // all waves done reading buf[cur] before it is re-staged
  }

#pragma unroll
  for (int r = 0; r < 4; ++r) {
    float inv = 1.f / lrow[r];
    int tg = qrow0 + (lane >> 4) * 4 + r;
    bf16* yp = y + ((size_t)(b * T + tg)) * (H * Dh) + h * Dh + (lane & 15);
#pragma unroll
    for (int dc = 0; dc < 8; ++dc)
      yp[dc * 16] = __float2bfloat16(acc_o[dc][r] * inv);
  }
}

// ---------------- launch ----------------
extern "C" void kernel_launch(void* const* d_in, const int* in_sizes, int n_in,
                              void* d_out, int out_size, void* d_ws, size_t ws_size,
                              hipStream_t stream) {
  const float* x    = (const float*)d_in[0];
  const float* cosp = (const float*)d_in[1];
  const float* sinp = (const float*)d_in[2];
  const float* wq   = (const float*)d_in[3];
  const float* wk   = (const float*)d_in[4];
  const float* wv   = (const float*)d_in[5];
  const float* wp   = (const float*)d_in[6];
  float* out = (float*)d_out;

  constexpr size_t Mtok = 8192;  // B*T
  constexpr int Cdim = 2048, HD = 2048, KVD = 512;

  char* ws = (char*)d_ws;
  bf16* xb  = (bf16*)ws; ws += Mtok * Cdim * 2;
  bf16* wqT = (bf16*)ws; ws += (size_t)HD * Cdim * 2;
  bf16* wkT = (bf16*)ws; ws += (size_t)KVD * Cdim * 2;
  bf16* wvT = (bf16*)ws; ws += (size_t)KVD * Cdim * 2;
  bf16* wpT = (bf16*)ws; ws += (size_t)Cdim * HD * 2;
  bf16* qb  = (bf16*)ws; ws += Mtok * HD * 2;
  bf16* kb  = (bf16*)ws; ws += Mtok * KVD * 2;
  bf16* vb  = (bf16*)ws; ws += Mtok * KVD * 2;
  bf16* vtb = (bf16*)ws; ws += Mtok * KVD * 2;
  bf16* yb  = (bf16*)ws; ws += Mtok * HD * 2;

  f32_to_bf16_k<<<dim3(Mtok * Cdim / 8 / 256), 256, 0, stream>>>(x, xb, Mtok * Cdim);
  transpose_cvt_k<<<dim3(HD / 32, Cdim / 32), 256, 0, stream>>>(wq, wqT, Cdim, HD);
  transpose_cvt_k<<<dim3(KVD / 32, Cdim / 32), 256, 0, stream>>>(wk, wkT, Cdim, KVD);
  transpose_cvt_k<<<dim3(KVD / 32, Cdim / 32), 256, 0, stream>>>(wv, wvT, Cdim, KVD);
  transpose_cvt_k<<<dim3(Cdim / 32, HD / 32), 256, 0, stream>>>(wp, wpT, HD, Cdim);

  gemm_bt<bf16><<<dim3(64, 16), 256, 0, stream>>>(xb, wqT, qb, (int)Mtok, HD, Cdim);
  gemm_bt<bf16><<<dim3(64, 4), 256, 0, stream>>>(xb, wkT, kb, (int)Mtok, KVD, Cdim);
  gemm_bt<bf16><<<dim3(64, 4), 256, 0, stream>>>(xb, wvT, vb, (int)Mtok, KVD, Cdim);

  rope_rms_k<<<dim3(Mtok * 16 / 4), 256, 0, stream>>>(qb, cosp, sinp, 16, 0.08838834764831845f);
  rope_rms_k<<<dim3(Mtok * 4 / 4), 256, 0, stream>>>(kb, cosp, sinp, 4, 1.0f);
  transpose_v_k<<<dim3(64, 4, 16), 256, 0, stream>>>(vb, vtb);

  attn_k<<<dim3(1024), 512, 0, stream>>>(qb, kb, vtb, yb);

  gemm_bt<float><<<dim3(64, 16), 256, 0, stream>>>(yb, wpT, out, (int)Mtok, HD, Cdim);
}

// Round 3
// 466.326 us; speedup vs baseline: 1.8216x; 1.1490x over previous
//
#include <hip/hip_runtime.h>
#include <hip/hip_bf16.h>
#include <stdint.h>

using bf16 = __hip_bfloat16;
typedef __attribute__((ext_vector_type(8))) short short8;
typedef __attribute__((ext_vector_type(4))) float f32x4;

#define MFMA16(a,b,c) __builtin_amdgcn_mfma_f32_16x16x32_bf16(a,b,c,0,0,0)

__device__ __forceinline__ void gload_lds16(const void* g, void* l) {
  __builtin_amdgcn_global_load_lds((const __attribute__((address_space(1))) void*)g,
                                   (__attribute__((address_space(3))) void*)l, 16, 0, 0);
}

__device__ __forceinline__ short bf_bits(float f) {
  bf16 h = __float2bfloat16(f);
  return *reinterpret_cast<short*>(&h);
}

// ---------------- f32 -> bf16 elementwise (8/thread) ----------------
__global__ __launch_bounds__(256) void f32_to_bf16_k(const float* __restrict__ in,
                                                     bf16* __restrict__ out, size_t n) {
  size_t i = ((size_t)blockIdx.x * 256 + threadIdx.x) * 8;
  if (i >= n) return;
  float4 a = *(const float4*)(in + i);
  float4 b = *(const float4*)(in + i + 4);
  short8 pk;
  pk[0] = bf_bits(a.x); pk[1] = bf_bits(a.y); pk[2] = bf_bits(a.z); pk[3] = bf_bits(a.w);
  pk[4] = bf_bits(b.x); pk[5] = bf_bits(b.y); pk[6] = bf_bits(b.z); pk[7] = bf_bits(b.w);
  *(short8*)(out + i) = pk;
}

// ---------------- transpose + convert: in[K][N] f32 -> out[N][K] bf16 ----------------
// out may point into a larger row-block (caller offsets); out rows are K elements.
__global__ __launch_bounds__(256) void transpose_cvt_k(const float* __restrict__ in,
                                                       bf16* __restrict__ out, int K, int N) {
  __shared__ float tile[32][33];
  int n0 = blockIdx.x * 32, k0 = blockIdx.y * 32;
  int tx = threadIdx.x & 31, ty = threadIdx.x >> 5;  // 32 x 8
#pragma unroll
  for (int j = 0; j < 4; ++j) {
    int kk = ty + j * 8;
    tile[kk][tx] = in[(size_t)(k0 + kk) * N + n0 + tx];
  }
  __syncthreads();
#pragma unroll
  for (int j = 0; j < 4; ++j) {
    int nn = ty + j * 8;
    out[(size_t)(n0 + nn) * K + k0 + tx] = __float2bfloat16(tile[tx][nn]);
  }
}

// ---------------- V transpose: qkv[(b*T+t)][2560 + kv*128 + d] -> vt[((b*4+kv)*128+d)][t] ----------------
__global__ __launch_bounds__(256) void transpose_v_k(const bf16* __restrict__ qkv,
                                                     bf16* __restrict__ vt) {
  constexpr int T = 2048, Dh = 128, KV = 4, QKVW = 3072, VOFF = 2560;
  __shared__ bf16 tile[32][33];
  int t0 = blockIdx.x * 32, d0 = blockIdx.y * 32;
  int b = blockIdx.z >> 2, kv = blockIdx.z & 3;
  int tx = threadIdx.x & 31, ty = threadIdx.x >> 5;
#pragma unroll
  for (int j = 0; j < 4; ++j) {
    int tt = ty + j * 8;
    tile[tt][tx] = qkv[((size_t)(b * T + t0 + tt)) * QKVW + VOFF + kv * Dh + d0 + tx];
  }
  __syncthreads();
#pragma unroll
  for (int j = 0; j < 4; ++j) {
    int dd = ty + j * 8;
    vt[((size_t)((b * KV + kv) * Dh + d0 + dd)) * T + t0 + tx] = tile[tx][dd];
  }
}

// ---------------- fused RoPE + RMSNorm (in place), 1 wave per (token,head) row ----------------
__global__ __launch_bounds__(256) void rope_rms_k(bf16* __restrict__ buf, int rowstride,
                                                  int baseoff,
                                                  const float* __restrict__ cosp,
                                                  const float* __restrict__ sinp,
                                                  int nh, float outscale) {
  constexpr int T = 2048;
  int wid = blockIdx.x * 4 + (threadIdx.x >> 6);
  int lane = threadIdx.x & 63;
  int h = wid % nh;
  int tok = wid / nh;          // b*T + t
  int t = tok & (T - 1);
  bf16* p = buf + (size_t)tok * rowstride + baseoff + h * 128;
  float x1 = __bfloat162float(p[lane]);
  float x2 = __bfloat162float(p[lane + 64]);
  float c = cosp[t * 64 + lane], s = sinp[t * 64 + lane];
  float o1 = x1 * c - x2 * s;
  float o2 = x1 * s + x2 * c;
  float ss = o1 * o1 + o2 * o2;
#pragma unroll
  for (int m = 1; m < 64; m <<= 1) ss += __shfl_xor(ss, m, 64);
  float r = rsqrtf(ss * (1.f / 128.f) + 1e-5f) * outscale;
  p[lane] = __float2bfloat16(o1 * r);
  p[lane + 64] = __float2bfloat16(o2 * r);
}

// ---------------- bf16 GEMM: C[M][N] = A[M][K] * Bt[N][K]^T ----------------
// 1D grid (nwg % 8 == 0), XCD-bijective swizzle, nt-fastest within XCD chunk.
// bf16 output goes through an LDS-staged coalesced epilogue.
template <typename OutT>
__global__ __launch_bounds__(256) void gemm_bt(const bf16* __restrict__ A,
                                               const bf16* __restrict__ Bt,
                                               OutT* __restrict__ C, int M, int N, int K,
                                               int NT) {
  constexpr int BM = 128, BN = 128, BK = 64;
  __shared__ char smem[32768];
  bf16* sA = (bf16*)smem;             // [BM][BK]
  bf16* sB = (bf16*)(smem + 16384);   // [BN][BK]
  int tid = threadIdx.x;
  int lane = tid & 63, w = tid >> 6;
  // XCD swizzle: dispatcher round-robins blockIdx%8 across XCDs; give each XCD a
  // contiguous wgid chunk (nt fastest -> B panels L2/L3-resident, A-panel per chunk).
  int flat = blockIdx.x;
  int wgid = (flat & 7) * (gridDim.x >> 3) + (flat >> 3);
  int m0 = (wgid / NT) * BM, n0 = (wgid % NT) * BN;
  int wm = (w >> 1) * 64, wn = (w & 1) * 64;
  f32x4 acc[4][4] = {};
  int nk = K / BK;
  for (int kt = 0; kt < nk; ++kt) {
    __syncthreads();
    int kb = kt * BK;
#pragma unroll
    for (int it = 0; it < 4; ++it) {
      int off = tid * 16 + it * 4096;
      int row = off >> 7, cb = off & 127;
      gload_lds16((const char*)A + (((size_t)(m0 + row)) * K + kb) * 2 + cb, (char*)sA + off);
    }
#pragma unroll
    for (int it = 0; it < 4; ++it) {
      int off = tid * 16 + it * 4096;
      int row = off >> 7, cb = off & 127;
      gload_lds16((const char*)Bt + (((size_t)(n0 + row)) * K + kb) * 2 + cb, (char*)sB + off);
    }
    asm volatile("s_waitcnt vmcnt(0)" ::: "memory");
    __syncthreads();
#pragma unroll
    for (int ks = 0; ks < 2; ++ks) {
      short8 af[4], bfr[4];
#pragma unroll
      for (int i = 0; i < 4; ++i) {
        af[i]  = *(const short8*)(sA + (wm + i * 16 + (lane & 15)) * BK + ks * 32 + (lane >> 4) * 8);
        bfr[i] = *(const short8*)(sB + (wn + i * 16 + (lane & 15)) * BK + ks * 32 + (lane >> 4) * 8);
      }
#pragma unroll
      for (int i = 0; i < 4; ++i)
#pragma unroll
        for (int j = 0; j < 4; ++j)
          acc[i][j] = MFMA16(af[i], bfr[j], acc[i][j]);
    }
  }
  if constexpr (sizeof(OutT) == 2) {
    // stage C tile (128x128 bf16 = 32 KB) in LDS, then coalesced dwordx4 stores
    __syncthreads();
    bf16* sC = (bf16*)smem;
#pragma unroll
    for (int i = 0; i < 4; ++i) {
      int row = wm + i * 16 + (lane >> 4) * 4;
#pragma unroll
      for (int j = 0; j < 4; ++j) {
        int col = wn + j * 16 + (lane & 15);
#pragma unroll
        for (int r = 0; r < 4; ++r)
          sC[(row + r) * BN + col] = __float2bfloat16(acc[i][j][r]);
      }
    }
    __syncthreads();
#pragma unroll
    for (int it = 0; it < 8; ++it) {
      int off = tid * 16 + it * 4096;
      int row = off >> 8, cb = off & 255;
      *(short8*)((char*)C + ((size_t)(m0 + row) * N + n0) * 2 + cb) =
          *(const short8*)(smem + off);
    }
  } else {
#pragma unroll
    for (int i = 0; i < 4; ++i) {
      int row = m0 + wm + i * 16 + (lane >> 4) * 4;
#pragma unroll
      for (int j = 0; j < 4; ++j) {
        int col = n0 + wn + j * 16 + (lane & 15);
#pragma unroll
        for (int r = 0; r < 4; ++r)
          C[(size_t)(row + r) * N + col] = acc[i][j][r];
      }
    }
  }
}

// ---------------- flash attention (swizzled LDS, double-buffered K/V, defer-max) ----------------
// qkv[(b*T+t)][3072]: q at h*128, k at 2048+kh*128. vt[((b*4+kv)*128+d)][t]
__global__ __launch_bounds__(512) void attn_k(const bf16* __restrict__ qkv,
                                              const bf16* __restrict__ vt,
                                              bf16* __restrict__ y) {
  constexpr int T = 2048, Dh = 128, H = 16, KV = 4, QB = 128, KB = 64, QKVW = 3072, KOFF = 2048;
  __shared__ bf16 sK[2 * 64 * 128];
  __shared__ bf16 sV[2 * 128 * 64];
  __shared__ bf16 sP[8 * 16 * 64];
  int tid = threadIdx.x, lane = tid & 63, w = tid >> 6;
  int bx = blockIdx.x;
  int qt = 15 - (bx >> 6);               // longest blocks first
  int b = (bx >> 4) & 3, h = bx & 15;
  int kh = h >> 2;
  int qrow0 = qt * QB + w * 16;
  const int sw = (lane & 7) << 4;
  const int cb0 = (lane >> 4) << 4;

  short8 aq[4];
  {
    int t0 = qrow0 + (lane & 15);
    const bf16* qp = qkv + ((size_t)(b * T + t0)) * QKVW + h * Dh + (lane >> 4) * 8;
#pragma unroll
    for (int ks = 0; ks < 4; ++ks) aq[ks] = *(const short8*)(qp + ks * 32);
  }
  __builtin_amdgcn_s_waitcnt(0);

  f32x4 acc_o[8];
#pragma unroll
  for (int i = 0; i < 8; ++i) acc_o[i] = (f32x4){0.f, 0.f, 0.f, 0.f};
  float mrow[4], lrow[4];
#pragma unroll
  for (int r = 0; r < 4; ++r) { mrow[r] = -INFINITY; lrow[r] = 0.f; }

  auto stage = [&](int buf, int kv0) {
#pragma unroll
    for (int p = 0; p < 2; ++p) {  // K: 64 rows x 256B
      int off = tid * 16 + p * 8192;
      int row = off >> 8, cb = off & 255;
      int scb = cb ^ ((row & 7) << 4);
      gload_lds16((const char*)qkv + (((size_t)(b * T + kv0 + row)) * QKVW + KOFF + kh * Dh) * 2 + scb,
                  (char*)sK + buf * 16384 + off);
    }
#pragma unroll
    for (int p = 0; p < 2; ++p) {  // Vt: 128 rows x 128B
      int off = tid * 16 + p * 8192;
      int row = off >> 7, cb = off & 127;
      int scb = cb ^ ((row & 7) << 4);
      gload_lds16((const char*)vt + (((size_t)((b * KV + kh) * Dh + row)) * T + kv0) * 2 + scb,
                  (char*)sV + buf * 16384 + off);
    }
  };

  int nt = qt * 2 + 2;
  stage(0, 0);
  char* myP = (char*)sP + w * 2048;

  for (int it = 0; it < nt; ++it) {
    int cur = it & 1;
    if (it + 1 < nt) {
      stage(cur ^ 1, (it + 1) * KB);
      asm volatile("s_waitcnt vmcnt(4)" ::: "memory");
    } else {
      asm volatile("s_waitcnt vmcnt(0)" ::: "memory");
    }
    __builtin_amdgcn_s_barrier();
    const char* sKc = (const char*)sK + cur * 16384;
    const char* sVc = (const char*)sV + cur * 16384;

    // ---- QK^T ----
    f32x4 s[4];
#pragma unroll
    for (int c = 0; c < 4; ++c) s[c] = (f32x4){0.f, 0.f, 0.f, 0.f};
    __builtin_amdgcn_s_setprio(1);
#pragma unroll
    for (int ks = 0; ks < 4; ++ks) {
#pragma unroll
      for (int c = 0; c < 4; ++c) {
        short8 bk = *(const short8*)(sKc + ((c * 16 + (lane & 15)) << 8) + ((ks * 64 + cb0) ^ sw));
        s[c] = MFMA16(aq[ks], bk, s[c]);
      }
    }
    __builtin_amdgcn_s_setprio(0);

    int kv0 = it * KB;
    if (it >= nt - 2) {
#pragma unroll
      for (int c = 0; c < 4; ++c) {
        int kvg = kv0 + c * 16 + (lane & 15);
#pragma unroll
        for (int r = 0; r < 4; ++r) {
          int qg = qrow0 + (lane >> 4) * 4 + r;
          if (kvg > qg) s[c][r] = -INFINITY;
        }
      }
    }

    // ---- online softmax with defer-max (T13, THR=8) ----
    float mt_[4];
    float need = -INFINITY;
#pragma unroll
    for (int r = 0; r < 4; ++r) {
      float mt = fmaxf(fmaxf(s[0][r], s[1][r]), fmaxf(s[2][r], s[3][r]));
#pragma unroll
      for (int m = 1; m < 16; m <<= 1) mt = fmaxf(mt, __shfl_xor(mt, m, 64));
      mt_[r] = mt;
      need = fmaxf(need, mt - mrow[r]);
    }
    if (!__all(need <= 8.0f)) {
#pragma unroll
      for (int r = 0; r < 4; ++r) {
        float mn = fmaxf(mrow[r], mt_[r]);
        float corr = __expf(mrow[r] - mn);
        mrow[r] = mn;
        lrow[r] *= corr;
#pragma unroll
        for (int dc = 0; dc < 8; ++dc) acc_o[dc][r] *= corr;
      }
    }
    float pv[4][4];
#pragma unroll
    for (int r = 0; r < 4; ++r) {
      float rsum = 0.f;
#pragma unroll
      for (int c = 0; c < 4; ++c) { float e = __expf(s[c][r] - mrow[r]); pv[c][r] = e; rsum += e; }
#pragma unroll
      for (int m = 1; m < 16; m <<= 1) rsum += __shfl_xor(rsum, m, 64);
      lrow[r] += rsum;
    }

    // ---- P -> LDS (swizzled write), reload as A-fragment ----
#pragma unroll
    for (int c = 0; c < 4; ++c)
#pragma unroll
      for (int r = 0; r < 4; ++r) {
        int prow = ((lane >> 4) << 2) + r;
        *(bf16*)(myP + (prow << 7) + ((((c * 16 + (lane & 15)) << 1)) ^ ((prow & 7) << 4))) =
            __float2bfloat16(pv[c][r]);
      }

    // ---- PV ----
    __builtin_amdgcn_s_setprio(1);
#pragma unroll
    for (int ks = 0; ks < 2; ++ks) {
      short8 pa = *(const short8*)(myP + ((lane & 15) << 7) + ((ks * 64 + cb0) ^ sw));
#pragma unroll
      for (int dc = 0; dc < 8; ++dc) {
        short8 bv = *(const short8*)(sVc + ((dc * 16 + (lane & 15)) << 7) + ((ks * 64 + cb0) ^ sw));
        acc_o[dc] = MFMA16(pa, bv, acc_o[dc]);
      }
    }
    __builtin_amdgcn_s_setprio(0);
    __builtin_amdgcn_s_barrier();
  }

#pragma unroll
  for (int r = 0; r < 4; ++r) {
    float inv = 1.f / lrow[r];
    int tg = qrow0 + (lane >> 4) * 4 + r;
    bf16* yp = y + ((size_t)(b * T + tg)) * (H * Dh) + h * Dh + (lane & 15);
#pragma unroll
    for (int dc = 0; dc < 8; ++dc)
      yp[dc * 16] = __float2bfloat16(acc_o[dc][r] * inv);
  }
}

// ---------------- launch ----------------
extern "C" void kernel_launch(void* const* d_in, const int* in_sizes, int n_in,
                              void* d_out, int out_size, void* d_ws, size_t ws_size,
                              hipStream_t stream) {
  const float* x    = (const float*)d_in[0];
  const float* cosp = (const float*)d_in[1];
  const float* sinp = (const float*)d_in[2];
  const float* wq   = (const float*)d_in[3];
  const float* wk   = (const float*)d_in[4];
  const float* wv   = (const float*)d_in[5];
  const float* wp   = (const float*)d_in[6];
  float* out = (float*)d_out;

  constexpr size_t Mtok = 8192;  // B*T
  constexpr int Cdim = 2048, HD = 2048, KVD = 512, QKVW = 3072;

  char* ws = (char*)d_ws;
  bf16* xb    = (bf16*)ws; ws += Mtok * Cdim * 2;
  bf16* wqkvT = (bf16*)ws; ws += (size_t)QKVW * Cdim * 2;  // rows: wq^T | wk^T | wv^T
  bf16* wpT   = (bf16*)ws; ws += (size_t)Cdim * HD * 2;
  bf16* qkv   = (bf16*)ws; ws += Mtok * QKVW * 2;
  bf16* vtb   = (bf16*)ws; ws += Mtok * KVD * 2;
  bf16* yb    = (bf16*)ws; ws += Mtok * HD * 2;

  f32_to_bf16_k<<<dim3(Mtok * Cdim / 8 / 256), 256, 0, stream>>>(x, xb, Mtok * Cdim);
  transpose_cvt_k<<<dim3(HD / 32, Cdim / 32), 256, 0, stream>>>(wq, wqkvT, Cdim, HD);
  transpose_cvt_k<<<dim3(KVD / 32, Cdim / 32), 256, 0, stream>>>(wk, wqkvT + (size_t)2048 * Cdim, Cdim, KVD);
  transpose_cvt_k<<<dim3(KVD / 32, Cdim / 32), 256, 0, stream>>>(wv, wqkvT + (size_t)2560 * Cdim, Cdim, KVD);
  transpose_cvt_k<<<dim3(Cdim / 32, HD / 32), 256, 0, stream>>>(wp, wpT, HD, Cdim);

  // fused QKV projection: [8192 x 3072] = xb [8192 x 2048] * wqkvT^T
  gemm_bt<bf16><<<dim3(64 * 24), 256, 0, stream>>>(xb, wqkvT, qkv, (int)Mtok, QKVW, Cdim, 24);

  rope_rms_k<<<dim3(Mtok * 16 / 4), 256, 0, stream>>>(qkv, QKVW, 0, cosp, sinp, 16,
                                                      0.08838834764831845f);
  rope_rms_k<<<dim3(Mtok * 4 / 4), 256, 0, stream>>>(qkv, QKVW, 2048, cosp, sinp, 4, 1.0f);
  transpose_v_k<<<dim3(64, 4, 16), 256, 0, stream>>>(qkv, vtb);

  attn_k<<<dim3(1024), 512, 0, stream>>>(qkv, vtb, yb);

  gemm_bt<float><<<dim3(64 * 16), 256, 0, stream>>>(yb, wpT, out, (int)Mtok, HD, Cdim, 16);
}

// Round 4
// 396.291 us; speedup vs baseline: 2.1435x; 1.1767x over previous
//
#include <hip/hip_runtime.h>
#include <hip/hip_bf16.h>
#include <stdint.h>

using bf16 = __hip_bfloat16;
typedef __attribute__((ext_vector_type(8))) short short8;
typedef __attribute__((ext_vector_type(4))) float f32x4;

#define MFMA16(a,b,c) __builtin_amdgcn_mfma_f32_16x16x32_bf16(a,b,c,0,0,0)

__device__ __forceinline__ void gload_lds16(const void* g, void* l) {
  __builtin_amdgcn_global_load_lds((const __attribute__((address_space(1))) void*)g,
                                   (__attribute__((address_space(3))) void*)l, 16, 0, 0);
}

__device__ __forceinline__ short bf_bits(float f) {
  bf16 h = __float2bfloat16(f);
  return *reinterpret_cast<short*>(&h);
}

// ---------------- f32 -> bf16 elementwise (8/thread) ----------------
__global__ __launch_bounds__(256) void f32_to_bf16_k(const float* __restrict__ in,
                                                     bf16* __restrict__ out, size_t n) {
  size_t i = ((size_t)blockIdx.x * 256 + threadIdx.x) * 8;
  if (i >= n) return;
  float4 a = *(const float4*)(in + i);
  float4 b = *(const float4*)(in + i + 4);
  short8 pk;
  pk[0] = bf_bits(a.x); pk[1] = bf_bits(a.y); pk[2] = bf_bits(a.z); pk[3] = bf_bits(a.w);
  pk[4] = bf_bits(b.x); pk[5] = bf_bits(b.y); pk[6] = bf_bits(b.z); pk[7] = bf_bits(b.w);
  *(short8*)(out + i) = pk;
}

// ---------------- transpose + convert: in[K][N] f32 -> out[N][K] bf16 ----------------
__global__ __launch_bounds__(256) void transpose_cvt_k(const float* __restrict__ in,
                                                       bf16* __restrict__ out, int K, int N) {
  __shared__ float tile[32][33];
  int n0 = blockIdx.x * 32, k0 = blockIdx.y * 32;
  int tx = threadIdx.x & 31, ty = threadIdx.x >> 5;  // 32 x 8
#pragma unroll
  for (int j = 0; j < 4; ++j) {
    int kk = ty + j * 8;
    tile[kk][tx] = in[(size_t)(k0 + kk) * N + n0 + tx];
  }
  __syncthreads();
#pragma unroll
  for (int j = 0; j < 4; ++j) {
    int nn = ty + j * 8;
    out[(size_t)(n0 + nn) * K + k0 + tx] = __float2bfloat16(tile[tx][nn]);
  }
}

// ---------------- V transpose: qkv[(b*T+t)][2560 + kv*128 + d] -> vt[((b*4+kv)*128+d)][t] ----------------
__global__ __launch_bounds__(256) void transpose_v_k(const bf16* __restrict__ qkv,
                                                     bf16* __restrict__ vt) {
  constexpr int T = 2048, Dh = 128, KV = 4, QKVW = 3072, VOFF = 2560;
  __shared__ bf16 tile[32][33];
  int t0 = blockIdx.x * 32, d0 = blockIdx.y * 32;
  int b = blockIdx.z >> 2, kv = blockIdx.z & 3;
  int tx = threadIdx.x & 31, ty = threadIdx.x >> 5;
#pragma unroll
  for (int j = 0; j < 4; ++j) {
    int tt = ty + j * 8;
    tile[tt][tx] = qkv[((size_t)(b * T + t0 + tt)) * QKVW + VOFF + kv * Dh + d0 + tx];
  }
  __syncthreads();
#pragma unroll
  for (int j = 0; j < 4; ++j) {
    int dd = ty + j * 8;
    vt[((size_t)((b * KV + kv) * Dh + d0 + dd)) * T + t0 + tx] = tile[tx][dd];
  }
}

// ---------------- fused RoPE + RMSNorm (in place), 1 wave per (token,head) row ----------------
__global__ __launch_bounds__(256) void rope_rms_k(bf16* __restrict__ buf, int rowstride,
                                                  int baseoff,
                                                  const float* __restrict__ cosp,
                                                  const float* __restrict__ sinp,
                                                  int nh, float outscale) {
  constexpr int T = 2048;
  int wid = blockIdx.x * 4 + (threadIdx.x >> 6);
  int lane = threadIdx.x & 63;
  int h = wid % nh;
  int tok = wid / nh;          // b*T + t
  int t = tok & (T - 1);
  bf16* p = buf + (size_t)tok * rowstride + baseoff + h * 128;
  float x1 = __bfloat162float(p[lane]);
  float x2 = __bfloat162float(p[lane + 64]);
  float c = cosp[t * 64 + lane], s = sinp[t * 64 + lane];
  float o1 = x1 * c - x2 * s;
  float o2 = x1 * s + x2 * c;
  float ss = o1 * o1 + o2 * o2;
#pragma unroll
  for (int m = 1; m < 64; m <<= 1) ss += __shfl_xor(ss, m, 64);
  float r = rsqrtf(ss * (1.f / 128.f) + 1e-5f) * outscale;
  p[lane] = __float2bfloat16(o1 * r);
  p[lane + 64] = __float2bfloat16(o2 * r);
}

// ---------------- 256x256 8-phase bf16 GEMM: C[M][N] = A[M][K] * Bt[N][K]^T ----------------
// 512 threads = 8 waves (2M x 4N). BK=64, 2 K-tiles/iter, 8 phases/iter.
// LDS 128 KiB: buf d at d*65536 { A[256][64] at +0, B[256][64] at +32768 }, 128B rows,
// XOR-swizzle byte^=((row&7)<<4) applied on global source (staging) and ds_read.
// Stage schedule: P1,P2=buf1.A(t1) P3,P4=buf0.B(t0+2) P5,P6=buf0.A(t0+2) P7,P8=buf1.B(t1+2).
// vmcnt(4) ONLY at end of P4 and P8 (2 half-tiles = 4 loads stay in flight).
#define PHASE(buf, i0, ...)                                                       \
  {                                                                               \
    short8 a00 = ldA(buf, i0, 0), a01 = ldA(buf, i0, 1);                          \
    short8 a10 = ldA(buf, (i0) + 1, 0), a11 = ldA(buf, (i0) + 1, 1);              \
    __VA_ARGS__;                                                                  \
    __builtin_amdgcn_s_barrier();                                                 \
    asm volatile("s_waitcnt lgkmcnt(0)" ::: "memory");                            \
    __builtin_amdgcn_s_setprio(1);                                                \
    _Pragma("unroll") for (int j = 0; j < 4; ++j) {                               \
      acc[i0][j] = MFMA16(a00, bf_[2 * j], acc[i0][j]);                           \
      acc[i0][j] = MFMA16(a01, bf_[2 * j + 1], acc[i0][j]);                       \
      acc[(i0) + 1][j] = MFMA16(a10, bf_[2 * j], acc[(i0) + 1][j]);               \
      acc[(i0) + 1][j] = MFMA16(a11, bf_[2 * j + 1], acc[(i0) + 1][j]);           \
    }                                                                             \
    __builtin_amdgcn_s_setprio(0);                                                \
  }
#define LOADB(buf)                                                                \
  _Pragma("unroll") for (int j = 0; j < 4; ++j) {                                 \
    bf_[2 * j] = ldB(buf, j, 0);                                                  \
    bf_[2 * j + 1] = ldB(buf, j, 1);                                              \
  }
#define BAR __builtin_amdgcn_s_barrier()

template <typename OutT>
__global__ __launch_bounds__(512, 2) void gemm256(const bf16* __restrict__ A,
                                                  const bf16* __restrict__ Bt,
                                                  OutT* __restrict__ C, int M, int N, int K,
                                                  int NT) {
  __shared__ char lds[131072];
  const int tid = threadIdx.x, lane = tid & 63, w = tid >> 6;
  const int wm = w >> 2, wn = w & 3;
  const int bx = blockIdx.x;
  const int chunk = gridDim.x >> 3;
  const int wgid = (bx & 7) * chunk + (bx >> 3);   // XCD-bijective (grid % 8 == 0)
  const int m0 = (wgid / NT) * 256, n0 = (wgid % NT) * 256;
  const int lm = lane & 15;
  const int sw = (lane & 7) << 4;
  const int g16 = (lane >> 4) << 4;
  const size_t strideAB = (size_t)K * 2;  // bytes per row

  auto stageA = [&](int buf, int h, int t) {
#pragma unroll
    for (int p2 = 0; p2 < 2; ++p2) {
      int off = tid * 16 + p2 * 8192;
      int row = off >> 7, cb = off & 127;
      int scb = cb ^ ((row & 7) << 4);
      gload_lds16((const char*)A + (size_t)(m0 + h * 128 + row) * strideAB + t * 128 + scb,
                  lds + buf * 65536 + h * 16384 + off);
    }
  };
  auto stageB = [&](int buf, int h, int t) {
#pragma unroll
    for (int p2 = 0; p2 < 2; ++p2) {
      int off = tid * 16 + p2 * 8192;
      int row = off >> 7, cb = off & 127;
      int scb = cb ^ ((row & 7) << 4);
      gload_lds16((const char*)Bt + (size_t)(n0 + h * 128 + row) * strideAB + t * 128 + scb,
                  lds + buf * 65536 + 32768 + h * 16384 + off);
    }
  };
  auto ldA = [&](int buf, int i, int ks) {
    int row = wm * 128 + i * 16 + lm;
    return *(const short8*)(lds + buf * 65536 + row * 128 + ((ks * 64 + g16) ^ sw));
  };
  auto ldB = [&](int buf, int j, int ks) {
    int row = wn * 64 + j * 16 + lm;
    return *(const short8*)(lds + buf * 65536 + 32768 + row * 128 + ((ks * 64 + g16) ^ sw));
  };

  f32x4 acc[8][4] = {};
  short8 bf_[8];
  const int niter = K / 128;

  // prologue: buf0 <- t=0 (A+B), buf1.B <- t=1; drain buf0, keep buf1.B in flight
  stageA(0, 0, 0); stageA(0, 1, 0); stageB(0, 0, 0); stageB(0, 1, 0);
  stageB(1, 0, 1); stageB(1, 1, 1);
  asm volatile("s_waitcnt vmcnt(4)" ::: "memory");
  BAR;

  for (int i = 0; i < niter; ++i) {
    const int t0 = 2 * i, t1 = 2 * i + 1;
    const bool nl = (i + 1 < niter);
    // ---- K-tile t0 from buf0 ----
    LOADB(0);
    PHASE(0, 0, stageA(1, 0, t1)); BAR;
    PHASE(0, 2, stageA(1, 1, t1)); BAR;
    PHASE(0, 4, if (nl) stageB(0, 0, t0 + 2)); BAR;
    PHASE(0, 6, if (nl) stageB(0, 1, t0 + 2));
    if (nl) { asm volatile("s_waitcnt vmcnt(4)" ::: "memory"); }
    else    { asm volatile("s_waitcnt vmcnt(0)" ::: "memory"); }
    BAR;
    // ---- K-tile t1 from buf1 ----
    LOADB(1);
    PHASE(1, 0, if (nl) stageA(0, 0, t0 + 2)); BAR;
    PHASE(1, 2, if (nl) stageA(0, 1, t0 + 2)); BAR;
    PHASE(1, 4, if (nl) stageB(1, 0, t1 + 2)); BAR;
    PHASE(1, 6, if (nl) stageB(1, 1, t1 + 2));
    if (nl) { asm volatile("s_waitcnt vmcnt(4)" ::: "memory"); }
    BAR;
  }

  // ---------------- epilogue ----------------
  if constexpr (sizeof(OutT) == 2) {
    __syncthreads();  // LDS reuse for coalesced bf16 store: C tile 256x256 bf16 = 128 KB
    bf16* sC = (bf16*)lds;
#pragma unroll
    for (int i = 0; i < 8; ++i) {
      int row = wm * 128 + i * 16 + (lane >> 4) * 4;
#pragma unroll
      for (int j = 0; j < 4; ++j) {
        int col = wn * 64 + j * 16 + lm;
#pragma unroll
        for (int r = 0; r < 4; ++r) sC[(row + r) * 256 + col] = __float2bfloat16(acc[i][j][r]);
      }
    }
    __syncthreads();
#pragma unroll
    for (int p = 0; p < 16; ++p) {
      int off = tid * 16 + p * 8192;
      int row = off >> 9, cb = off & 511;
      *(short8*)((char*)C + ((size_t)(m0 + row) * N + n0) * 2 + cb) =
          *(const short8*)(lds + off);
    }
  } else {
#pragma unroll
    for (int i = 0; i < 8; ++i) {
      int row = m0 + wm * 128 + i * 16 + (lane >> 4) * 4;
#pragma unroll
      for (int j = 0; j < 4; ++j) {
        int col = n0 + wn * 64 + j * 16 + lm;
#pragma unroll
        for (int r = 0; r < 4; ++r) C[(size_t)(row + r) * N + col] = acc[i][j][r];
      }
    }
  }
}

// ---------------- flash attention (swizzled LDS, double-buffered K/V, defer-max) ----------------
// qkv[(b*T+t)][3072]: q at h*128, k at 2048+kh*128. vt[((b*4+kv)*128+d)][t]
__global__ __launch_bounds__(512) void attn_k(const bf16* __restrict__ qkv,
                                              const bf16* __restrict__ vt,
                                              bf16* __restrict__ y) {
  constexpr int T = 2048, Dh = 128, H = 16, KV = 4, QB = 128, KB = 64, QKVW = 3072, KOFF = 2048;
  __shared__ bf16 sK[2 * 64 * 128];
  __shared__ bf16 sV[2 * 128 * 64];
  __shared__ bf16 sP[8 * 16 * 64];
  int tid = threadIdx.x, lane = tid & 63, w = tid >> 6;
  int bx = blockIdx.x;
  int qt = 15 - (bx >> 6);               // longest blocks first
  int b = (bx >> 4) & 3, h = bx & 15;
  int kh = h >> 2;
  int qrow0 = qt * QB + w * 16;
  const int sw = (lane & 7) << 4;
  const int cb0 = (lane >> 4) << 4;

  short8 aq[4];
  {
    int t0 = qrow0 + (lane & 15);
    const bf16* qp = qkv + ((size_t)(b * T + t0)) * QKVW + h * Dh + (lane >> 4) * 8;
#pragma unroll
    for (int ks = 0; ks < 4; ++ks) aq[ks] = *(const short8*)(qp + ks * 32);
  }
  __builtin_amdgcn_s_waitcnt(0);

  f32x4 acc_o[8];
#pragma unroll
  for (int i = 0; i < 8; ++i) acc_o[i] = (f32x4){0.f, 0.f, 0.f, 0.f};
  float mrow[4], lrow[4];
#pragma unroll
  for (int r = 0; r < 4; ++r) { mrow[r] = -INFINITY; lrow[r] = 0.f; }

  auto stage = [&](int buf, int kv0) {
#pragma unroll
    for (int p = 0; p < 2; ++p) {  // K: 64 rows x 256B
      int off = tid * 16 + p * 8192;
      int row = off >> 8, cb = off & 255;
      int scb = cb ^ ((row & 7) << 4);
      gload_lds16((const char*)qkv + (((size_t)(b * T + kv0 + row)) * QKVW + KOFF + kh * Dh) * 2 + scb,
                  (char*)sK + buf * 16384 + off);
    }
#pragma unroll
    for (int p = 0; p < 2; ++p) {  // Vt: 128 rows x 128B
      int off = tid * 16 + p * 8192;
      int row = off >> 7, cb = off & 127;
      int scb = cb ^ ((row & 7) << 4);
      gload_lds16((const char*)vt + (((size_t)((b * KV + kh) * Dh + row)) * T + kv0) * 2 + scb,
                  (char*)sV + buf * 16384 + off);
    }
  };

  int nt = qt * 2 + 2;
  stage(0, 0);
  char* myP = (char*)sP + w * 2048;

  for (int it = 0; it < nt; ++it) {
    int cur = it & 1;
    if (it + 1 < nt) {
      stage(cur ^ 1, (it + 1) * KB);
      asm volatile("s_waitcnt vmcnt(4)" ::: "memory");
    } else {
      asm volatile("s_waitcnt vmcnt(0)" ::: "memory");
    }
    __builtin_amdgcn_s_barrier();
    const char* sKc = (const char*)sK + cur * 16384;
    const char* sVc = (const char*)sV + cur * 16384;

    // ---- QK^T ----
    f32x4 s[4];
#pragma unroll
    for (int c = 0; c < 4; ++c) s[c] = (f32x4){0.f, 0.f, 0.f, 0.f};
    __builtin_amdgcn_s_setprio(1);
#pragma unroll
    for (int ks = 0; ks < 4; ++ks) {
#pragma unroll
      for (int c = 0; c < 4; ++c) {
        short8 bk = *(const short8*)(sKc + ((c * 16 + (lane & 15)) << 8) + ((ks * 64 + cb0) ^ sw));
        s[c] = MFMA16(aq[ks], bk, s[c]);
      }
    }
    __builtin_amdgcn_s_setprio(0);

    int kv0 = it * KB;
    if (it >= nt - 2) {
#pragma unroll
      for (int c = 0; c < 4; ++c) {
        int kvg = kv0 + c * 16 + (lane & 15);
#pragma unroll
        for (int r = 0; r < 4; ++r) {
          int qg = qrow0 + (lane >> 4) * 4 + r;
          if (kvg > qg) s[c][r] = -INFINITY;
        }
      }
    }

    // ---- online softmax with defer-max (T13, THR=8) ----
    float mt_[4];
    float need = -INFINITY;
#pragma unroll
    for (int r = 0; r < 4; ++r) {
      float mt = fmaxf(fmaxf(s[0][r], s[1][r]), fmaxf(s[2][r], s[3][r]));
#pragma unroll
      for (int m = 1; m < 16; m <<= 1) mt = fmaxf(mt, __shfl_xor(mt, m, 64));
      mt_[r] = mt;
      need = fmaxf(need, mt - mrow[r]);
    }
    if (!__all(need <= 8.0f)) {
#pragma unroll
      for (int r = 0; r < 4; ++r) {
        float mn = fmaxf(mrow[r], mt_[r]);
        float corr = __expf(mrow[r] - mn);
        mrow[r] = mn;
        lrow[r] *= corr;
#pragma unroll
        for (int dc = 0; dc < 8; ++dc) acc_o[dc][r] *= corr;
      }
    }
    float pv[4][4];
#pragma unroll
    for (int r = 0; r < 4; ++r) {
      float rsum = 0.f;
#pragma unroll
      for (int c = 0; c < 4; ++c) { float e = __expf(s[c][r] - mrow[r]); pv[c][r] = e; rsum += e; }
#pragma unroll
      for (int m = 1; m < 16; m <<= 1) rsum += __shfl_xor(rsum, m, 64);
      lrow[r] += rsum;
    }

    // ---- P -> LDS (swizzled write), reload as A-fragment ----
#pragma unroll
    for (int c = 0; c < 4; ++c)
#pragma unroll
      for (int r = 0; r < 4; ++r) {
        int prow = ((lane >> 4) << 2) + r;
        *(bf16*)(myP + (prow << 7) + ((((c * 16 + (lane & 15)) << 1)) ^ ((prow & 7) << 4))) =
            __float2bfloat16(pv[c][r]);
      }

    // ---- PV ----
    __builtin_amdgcn_s_setprio(1);
#pragma unroll
    for (int ks = 0; ks < 2; ++ks) {
      short8 pa = *(const short8*)(myP + ((lane & 15) << 7) + ((ks * 64 + cb0) ^ sw));
#pragma unroll
      for (int dc = 0; dc < 8; ++dc) {
        short8 bv = *(const short8*)(sVc + ((dc * 16 + (lane & 15)) << 7) + ((ks * 64 + cb0) ^ sw));
        acc_o[dc] = MFMA16(pa, bv, acc_o[dc]);
      }
    }
    __builtin_amdgcn_s_setprio(0);
    __builtin_amdgcn_s_barrier();
  }

#pragma unroll
  for (int r = 0; r < 4; ++r) {
    float inv = 1.f / lrow[r];
    int tg = qrow0 + (lane >> 4) * 4 + r;
    bf16* yp = y + ((size_t)(b * T + tg)) * (H * Dh) + h * Dh + (lane & 15);
#pragma unroll
    for (int dc = 0; dc < 8; ++dc)
      yp[dc * 16] = __float2bfloat16(acc_o[dc][r] * inv);
  }
}

// ---------------- launch ----------------
extern "C" void kernel_launch(void* const* d_in, const int* in_sizes, int n_in,
                              void* d_out, int out_size, void* d_ws, size_t ws_size,
                              hipStream_t stream) {
  const float* x    = (const float*)d_in[0];
  const float* cosp = (const float*)d_in[1];
  const float* sinp = (const float*)d_in[2];
  const float* wq   = (const float*)d_in[3];
  const float* wk   = (const float*)d_in[4];
  const float* wv   = (const float*)d_in[5];
  const float* wp   = (const float*)d_in[6];
  float* out = (float*)d_out;

  constexpr size_t Mtok = 8192;  // B*T
  constexpr int Cdim = 2048, HD = 2048, KVD = 512, QKVW = 3072;

  char* ws = (char*)d_ws;
  bf16* xb    = (bf16*)ws; ws += Mtok * Cdim * 2;
  bf16* wqkvT = (bf16*)ws; ws += (size_t)QKVW * Cdim * 2;  // rows: wq^T | wk^T | wv^T
  bf16* wpT   = (bf16*)ws; ws += (size_t)Cdim * HD * 2;
  bf16* qkv   = (bf16*)ws; ws += Mtok * QKVW * 2;
  bf16* vtb   = (bf16*)ws; ws += Mtok * KVD * 2;
  bf16* yb    = (bf16*)ws; ws += Mtok * HD * 2;

  f32_to_bf16_k<<<dim3(Mtok * Cdim / 8 / 256), 256, 0, stream>>>(x, xb, Mtok * Cdim);
  transpose_cvt_k<<<dim3(HD / 32, Cdim / 32), 256, 0, stream>>>(wq, wqkvT, Cdim, HD);
  transpose_cvt_k<<<dim3(KVD / 32, Cdim / 32), 256, 0, stream>>>(wk, wqkvT + (size_t)2048 * Cdim, Cdim, KVD);
  transpose_cvt_k<<<dim3(KVD / 32, Cdim / 32), 256, 0, stream>>>(wv, wqkvT + (size_t)2560 * Cdim, Cdim, KVD);
  transpose_cvt_k<<<dim3(Cdim / 32, HD / 32), 256, 0, stream>>>(wp, wpT, HD, Cdim);

  // fused QKV projection: [8192 x 3072] = xb [8192 x 2048] * wqkvT^T
  gemm256<bf16><<<dim3(384), 512, 0, stream>>>(xb, wqkvT, qkv, (int)Mtok, QKVW, Cdim, 12);

  rope_rms_k<<<dim3(Mtok * 16 / 4), 256, 0, stream>>>(qkv, QKVW, 0, cosp, sinp, 16,
                                                      0.08838834764831845f);
  rope_rms_k<<<dim3(Mtok * 4 / 4), 256, 0, stream>>>(qkv, QKVW, 2048, cosp, sinp, 4, 1.0f);
  transpose_v_k<<<dim3(64, 4, 16), 256, 0, stream>>>(qkv, vtb);

  attn_k<<<dim3(1024), 512, 0, stream>>>(qkv, vtb, yb);

  gemm256<float><<<dim3(256), 512, 0, stream>>>(yb, wpT, out, (int)Mtok, HD, Cdim, 8);
}

// Round 6
// 342.274 us; speedup vs baseline: 2.4818x; 1.1578x over previous
//
#include <hip/hip_runtime.h>
#include <hip/hip_bf16.h>
#include <stdint.h>

using bf16 = __hip_bfloat16;
typedef __attribute__((ext_vector_type(8))) short short8;
typedef __attribute__((ext_vector_type(4))) float f32x4;
typedef __attribute__((ext_vector_type(16))) float f32x16;

#define MFMA16(a,b,c) __builtin_amdgcn_mfma_f32_16x16x32_bf16(a,b,c,0,0,0)
#define MFMA32(a,b,c) __builtin_amdgcn_mfma_f32_32x32x16_bf16(a,b,c,0,0,0)

__device__ __forceinline__ void gload_lds16(const void* g, void* l) {
  __builtin_amdgcn_global_load_lds((const __attribute__((address_space(1))) void*)g,
                                   (__attribute__((address_space(3))) void*)l, 16, 0, 0);
}

__device__ __forceinline__ short bf_bits(float f) {
  bf16 h = __float2bfloat16(f);
  return *reinterpret_cast<short*>(&h);
}
__device__ __forceinline__ unsigned int pk2(float a, float b) {
  return ((unsigned int)(unsigned short)bf_bits(b) << 16) | (unsigned short)bf_bits(a);
}

// ---------------- f32 -> bf16 elementwise (8/thread) ----------------
__global__ __launch_bounds__(256) void f32_to_bf16_k(const float* __restrict__ in,
                                                     bf16* __restrict__ out, size_t n) {
  size_t i = ((size_t)blockIdx.x * 256 + threadIdx.x) * 8;
  if (i >= n) return;
  float4 a = *(const float4*)(in + i);
  float4 b = *(const float4*)(in + i + 4);
  short8 pk;
  pk[0] = bf_bits(a.x); pk[1] = bf_bits(a.y); pk[2] = bf_bits(a.z); pk[3] = bf_bits(a.w);
  pk[4] = bf_bits(b.x); pk[5] = bf_bits(b.y); pk[6] = bf_bits(b.z); pk[7] = bf_bits(b.w);
  *(short8*)(out + i) = pk;
}

// ---------------- transpose + convert: in[K][N] f32 -> out[N][K] bf16 ----------------
__global__ __launch_bounds__(256) void transpose_cvt_k(const float* __restrict__ in,
                                                       bf16* __restrict__ out, int K, int N) {
  __shared__ float tile[32][33];
  int n0 = blockIdx.x * 32, k0 = blockIdx.y * 32;
  int tx = threadIdx.x & 31, ty = threadIdx.x >> 5;  // 32 x 8
#pragma unroll
  for (int j = 0; j < 4; ++j) {
    int kk = ty + j * 8;
    tile[kk][tx] = in[(size_t)(k0 + kk) * N + n0 + tx];
  }
  __syncthreads();
#pragma unroll
  for (int j = 0; j < 4; ++j) {
    int nn = ty + j * 8;
    out[(size_t)(n0 + nn) * K + k0 + tx] = __float2bfloat16(tile[tx][nn]);
  }
}

// ---------------- V transpose: qkv[(b*T+t)][2560 + kv*128 + d] -> vt[((b*4+kv)*128+d)][t] ----------------
__global__ __launch_bounds__(256) void transpose_v_k(const bf16* __restrict__ qkv,
                                                     bf16* __restrict__ vt) {
  constexpr int T = 2048, Dh = 128, KV = 4, QKVW = 3072, VOFF = 2560;
  __shared__ bf16 tile[32][33];
  int t0 = blockIdx.x * 32, d0 = blockIdx.y * 32;
  int b = blockIdx.z >> 2, kv = blockIdx.z & 3;
  int tx = threadIdx.x & 31, ty = threadIdx.x >> 5;
#pragma unroll
  for (int j = 0; j < 4; ++j) {
    int tt = ty + j * 8;
    tile[tt][tx] = qkv[((size_t)(b * T + t0 + tt)) * QKVW + VOFF + kv * Dh + d0 + tx];
  }
  __syncthreads();
#pragma unroll
  for (int j = 0; j < 4; ++j) {
    int dd = ty + j * 8;
    vt[((size_t)((b * KV + kv) * Dh + d0 + dd)) * T + t0 + tx] = tile[tx][dd];
  }
}

// ---------------- fused RoPE + RMSNorm (in place), 1 wave per (token,head) row ----------------
__global__ __launch_bounds__(256) void rope_rms_k(bf16* __restrict__ buf, int rowstride,
                                                  int baseoff,
                                                  const float* __restrict__ cosp,
                                                  const float* __restrict__ sinp,
                                                  int nh, float outscale) {
  constexpr int T = 2048;
  int wid = blockIdx.x * 4 + (threadIdx.x >> 6);
  int lane = threadIdx.x & 63;
  int h = wid % nh;
  int tok = wid / nh;          // b*T + t
  int t = tok & (T - 1);
  bf16* p = buf + (size_t)tok * rowstride + baseoff + h * 128;
  float x1 = __bfloat162float(p[lane]);
  float x2 = __bfloat162float(p[lane + 64]);
  float c = cosp[t * 64 + lane], s = sinp[t * 64 + lane];
  float o1 = x1 * c - x2 * s;
  float o2 = x1 * s + x2 * c;
  float ss = o1 * o1 + o2 * o2;
#pragma unroll
  for (int m = 1; m < 64; m <<= 1) ss += __shfl_xor(ss, m, 64);
  float r = rsqrtf(ss * (1.f / 128.f) + 1e-5f) * outscale;
  p[lane] = __float2bfloat16(o1 * r);
  p[lane + 64] = __float2bfloat16(o2 * r);
}

// ---------------- 256x256 8-phase bf16 GEMM: C[M][N] = A[M][K] * Bt[N][K]^T ----------------
#define PHASE(buf, i0, ...)                                                       \
  {                                                                               \
    short8 a00 = ldA(buf, i0, 0), a01 = ldA(buf, i0, 1);                          \
    short8 a10 = ldA(buf, (i0) + 1, 0), a11 = ldA(buf, (i0) + 1, 1);              \
    __VA_ARGS__;                                                                  \
    __builtin_amdgcn_s_barrier();                                                 \
    asm volatile("s_waitcnt lgkmcnt(0)" ::: "memory");                            \
    __builtin_amdgcn_s_setprio(1);                                                \
    _Pragma("unroll") for (int j = 0; j < 4; ++j) {                               \
      acc[i0][j] = MFMA16(a00, bf_[2 * j], acc[i0][j]);                           \
      acc[i0][j] = MFMA16(a01, bf_[2 * j + 1], acc[i0][j]);                       \
      acc[(i0) + 1][j] = MFMA16(a10, bf_[2 * j], acc[(i0) + 1][j]);               \
      acc[(i0) + 1][j] = MFMA16(a11, bf_[2 * j + 1], acc[(i0) + 1][j]);           \
    }                                                                             \
    __builtin_amdgcn_s_setprio(0);                                                \
  }
#define LOADB(buf)                                                                \
  _Pragma("unroll") for (int j = 0; j < 4; ++j) {                                 \
    bf_[2 * j] = ldB(buf, j, 0);                                                  \
    bf_[2 * j + 1] = ldB(buf, j, 1);                                              \
  }
#define BAR __builtin_amdgcn_s_barrier()

template <typename OutT>
__global__ __launch_bounds__(512, 2) void gemm256(const bf16* __restrict__ A,
                                                  const bf16* __restrict__ Bt,
                                                  OutT* __restrict__ C, int M, int N, int K,
                                                  int NT) {
  __shared__ char lds[131072];
  const int tid = threadIdx.x, lane = tid & 63, w = tid >> 6;
  const int wm = w >> 2, wn = w & 3;
  const int bx = blockIdx.x;
  const int chunk = gridDim.x >> 3;
  const int wgid = (bx & 7) * chunk + (bx >> 3);   // XCD-bijective (grid % 8 == 0)
  const int m0 = (wgid / NT) * 256, n0 = (wgid % NT) * 256;
  const int lm = lane & 15;
  const int sw = (lane & 7) << 4;
  const int g16 = (lane >> 4) << 4;
  const size_t strideAB = (size_t)K * 2;  // bytes per row

  auto stageA = [&](int buf, int h, int t) {
#pragma unroll
    for (int p2 = 0; p2 < 2; ++p2) {
      int off = tid * 16 + p2 * 8192;
      int row = off >> 7, cb = off & 127;
      int scb = cb ^ ((row & 7) << 4);
      gload_lds16((const char*)A + (size_t)(m0 + h * 128 + row) * strideAB + t * 128 + scb,
                  lds + buf * 65536 + h * 16384 + off);
    }
  };
  auto stageB = [&](int buf, int h, int t) {
#pragma unroll
    for (int p2 = 0; p2 < 2; ++p2) {
      int off = tid * 16 + p2 * 8192;
      int row = off >> 7, cb = off & 127;
      int scb = cb ^ ((row & 7) << 4);
      gload_lds16((const char*)Bt + (size_t)(n0 + h * 128 + row) * strideAB + t * 128 + scb,
                  lds + buf * 65536 + 32768 + h * 16384 + off);
    }
  };
  auto ldA = [&](int buf, int i, int ks) {
    int row = wm * 128 + i * 16 + lm;
    return *(const short8*)(lds + buf * 65536 + row * 128 + ((ks * 64 + g16) ^ sw));
  };
  auto ldB = [&](int buf, int j, int ks) {
    int row = wn * 64 + j * 16 + lm;
    return *(const short8*)(lds + buf * 65536 + 32768 + row * 128 + ((ks * 64 + g16) ^ sw));
  };

  f32x4 acc[8][4] = {};
  short8 bf_[8];
  const int niter = K / 128;

  stageA(0, 0, 0); stageA(0, 1, 0); stageB(0, 0, 0); stageB(0, 1, 0);
  stageB(1, 0, 1); stageB(1, 1, 1);
  asm volatile("s_waitcnt vmcnt(4)" ::: "memory");
  BAR;

  for (int i = 0; i < niter; ++i) {
    const int t0 = 2 * i, t1 = 2 * i + 1;
    const bool nl = (i + 1 < niter);
    LOADB(0);
    PHASE(0, 0, stageA(1, 0, t1)); BAR;
    PHASE(0, 2, stageA(1, 1, t1)); BAR;
    PHASE(0, 4, if (nl) stageB(0, 0, t0 + 2)); BAR;
    PHASE(0, 6, if (nl) stageB(0, 1, t0 + 2));
    if (nl) { asm volatile("s_waitcnt vmcnt(4)" ::: "memory"); }
    else    { asm volatile("s_waitcnt vmcnt(0)" ::: "memory"); }
    BAR;
    LOADB(1);
    PHASE(1, 0, if (nl) stageA(0, 0, t0 + 2)); BAR;
    PHASE(1, 2, if (nl) stageA(0, 1, t0 + 2)); BAR;
    PHASE(1, 4, if (nl) stageB(1, 0, t1 + 2)); BAR;
    PHASE(1, 6, if (nl) stageB(1, 1, t1 + 2));
    if (nl) { asm volatile("s_waitcnt vmcnt(4)" ::: "memory"); }
    BAR;
  }

  if constexpr (sizeof(OutT) == 2) {
    __syncthreads();
    bf16* sC = (bf16*)lds;
#pragma unroll
    for (int i = 0; i < 8; ++i) {
      int row = wm * 128 + i * 16 + (lane >> 4) * 4;
#pragma unroll
      for (int j = 0; j < 4; ++j) {
        int col = wn * 64 + j * 16 + lm;
#pragma unroll
        for (int r = 0; r < 4; ++r) sC[(row + r) * 256 + col] = __float2bfloat16(acc[i][j][r]);
      }
    }
    __syncthreads();
#pragma unroll
    for (int p = 0; p < 16; ++p) {
      int off = tid * 16 + p * 8192;
      int row = off >> 9, cb = off & 511;
      *(short8*)((char*)C + ((size_t)(m0 + row) * N + n0) * 2 + cb) =
          *(const short8*)(lds + off);
    }
  } else {
#pragma unroll
    for (int i = 0; i < 8; ++i) {
      int row = m0 + wm * 128 + i * 16 + (lane >> 4) * 4;
#pragma unroll
      for (int j = 0; j < 4; ++j) {
        int col = n0 + wn * 64 + j * 16 + lm;
#pragma unroll
        for (int r = 0; r < 4; ++r) C[(size_t)(row + r) * N + col] = acc[i][j][r];
      }
    }
  }
}

// ---------------- flash attention: 8-wave 32x32 swapped-QK^T (m214 structure) ----------------
// qkv[(b*T+t)][3072]: q at h*128, k at 2048+kh*128. vt[((b*4+kv)*128+d)][t]
// Per wave: 32 q-rows. S^T = mfma(K, Q) puts q = lane&31 -> softmax fully in-register.
// P -> PV B-fragments via 16 pack + 8 v_permlane32_swap (vdst = low-g word!).
__global__ __launch_bounds__(512, 2) void attn_k(const bf16* __restrict__ qkv,
                                                 const bf16* __restrict__ vt,
                                                 bf16* __restrict__ y) {
  constexpr int T = 2048, Dh = 128, KV = 4, KB = 64, QKVW = 3072, KOFF = 2048;
  __shared__ char lds[65536];  // K dbuf 2x16K @0, V^T dbuf 2x16K @32768; reused for O-transpose
  const int tid = threadIdx.x, lane = tid & 63, w = tid >> 6;
  const int hi = lane >> 5, lq = lane & 31;
  const int bx = blockIdx.x;
  const int qt = 7 - (bx >> 6);          // longest blocks dispatch first
  const int b = (bx >> 4) & 3, h = bx & 15;
  const int kh = h >> 2;
  const int q0 = qt * 256 + w * 32;      // wave's first q row
  const int qg = q0 + lq;                // lane's q row
  const int swz = (lane & 7) << 4;

  // Q fragments (B-operand): aq[m] = Q[qg][m*16 + hi*8 .. +8]
  short8 aq[8];
  {
    const bf16* qp = qkv + ((size_t)(b * T + qg)) * QKVW + h * Dh + hi * 8;
#pragma unroll
    for (int m = 0; m < 8; ++m) aq[m] = *(const short8*)(qp + m * 16);
  }
  __builtin_amdgcn_s_waitcnt(0);

  f32x16 acc[4] = {};                    // O^T d-tiles: row d_local, col q=lq
  float mrow = -1e4f, lrow = 0.f;

  auto stage = [&](int buf, int kv0) {
#pragma unroll
    for (int p = 0; p < 2; ++p) {        // K: [64 kv][256B]
      int off = tid * 16 + p * 8192;
      int row = off >> 8, cb = off & 255;
      int scb = cb ^ ((row & 7) << 4);
      gload_lds16((const char*)qkv + (((size_t)(b * T + kv0 + row)) * QKVW + KOFF + kh * Dh) * 2 + scb,
                  lds + buf * 16384 + off);
    }
#pragma unroll
    for (int p = 0; p < 2; ++p) {        // V^T: [128 d][128B]
      int off = tid * 16 + p * 8192;
      int row = off >> 7, cb = off & 127;
      int scb = cb ^ ((row & 7) << 4);
      gload_lds16((const char*)vt + (((size_t)((b * KV + kh) * Dh + row)) * T + kv0) * 2 + scb,
                  lds + 32768 + buf * 16384 + off);
    }
  };

  const int nt = (qt + 1) * 4;
  const int lastit = (q0 + 31) >> 6;     // last tile this wave computes
  stage(0, 0);

  for (int it = 0; it < nt; ++it) {
    int cur = it & 1;
    if (it + 1 < nt) { stage(cur ^ 1, (it + 1) * KB); asm volatile("s_waitcnt vmcnt(4)" ::: "memory"); }
    else             { asm volatile("s_waitcnt vmcnt(0)" ::: "memory"); }
    __builtin_amdgcn_s_barrier();
    if (it <= lastit) {
      const char* sK = lds + cur * 16384;
      const char* sV = lds + 32768 + cur * 16384;
      const int kv0 = it * KB;

      // ---- QK^T: S^T[kv][q], A=K (rows kv), B=Q (cols q) ----
      f32x16 s0 = {}, s1 = {};
      __builtin_amdgcn_s_setprio(1);
#pragma unroll
      for (int m = 0; m < 8; ++m) {
        short8 ak = *(const short8*)(sK + lq * 256 + ((m * 32 + hi * 16) ^ swz));
        s0 = MFMA32(ak, aq[m], s0);
      }
#pragma unroll
      for (int m = 0; m < 8; ++m) {
        short8 ak = *(const short8*)(sK + (32 + lq) * 256 + ((m * 32 + hi * 16) ^ swz));
        s1 = MFMA32(ak, aq[m], s1);
      }
      __builtin_amdgcn_s_setprio(0);

      // ---- causal mask (kv row = (r&3)+8*(r>>2)+4*hi) ----
      if (kv0 + 63 > q0) {
#pragma unroll
        for (int r = 0; r < 16; ++r) {
          int krow = (r & 3) + 8 * (r >> 2) + 4 * hi;
          if (kv0 + krow > qg) s0[r] = -1e30f;
          if (kv0 + 32 + krow > qg) s1[r] = -1e30f;
        }
      }

      // ---- online softmax, in-register (q = lq lane-local) ----
      float tmax = s0[0];
#pragma unroll
      for (int r = 1; r < 16; ++r) tmax = fmaxf(tmax, s0[r]);
#pragma unroll
      for (int r = 0; r < 16; ++r) tmax = fmaxf(tmax, s1[r]);
      tmax = fmaxf(tmax, __shfl_xor(tmax, 32, 64));
      if (!__all(tmax - mrow <= 8.0f)) {   // defer-max (T13)
        float mn = fmaxf(mrow, tmax);
        float corr = __expf(mrow - mn);
        mrow = mn;
        lrow *= corr;
#pragma unroll
        for (int dt = 0; dt < 4; ++dt)
#pragma unroll
          for (int r = 0; r < 16; ++r) acc[dt][r] *= corr;
      }
      float rsum = 0.f;
#pragma unroll
      for (int r = 0; r < 16; ++r) { s0[r] = __expf(s0[r] - mrow); rsum += s0[r]; }
#pragma unroll
      for (int r = 0; r < 16; ++r) { s1[r] = __expf(s1[r] - mrow); rsum += s1[r]; }
      rsum += __shfl_xor(rsum, 32, 64);
      lrow += rsum;

      // ---- P -> bf16 B-fragments: 16 packs + 8 permlane32_swap ----
      // lane (hi,lq) holds w[g][c] = (P[8g+4hi+2c], P[8g+4hi+2c+1]) = u[2g+c], g=0..7.
      // pb[kvs].q_j needs (P[16kvs+8hi+2j], +1): pair A=u[4kvs+c] (vdst) with
      // B=u[4kvs+2+c] (vsrc); after swap A'=q_{0,1}, B'=q_{2,3}.
      unsigned int u[16];
#pragma unroll
      for (int g = 0; g < 4; ++g) {
        u[g * 2 + 0] = pk2(s0[4 * g + 0], s0[4 * g + 1]);
        u[g * 2 + 1] = pk2(s0[4 * g + 2], s0[4 * g + 3]);
        u[8 + g * 2 + 0] = pk2(s1[4 * g + 0], s1[4 * g + 1]);
        u[8 + g * 2 + 1] = pk2(s1[4 * g + 2], s1[4 * g + 3]);
      }
      short8 pb[4];
#pragma unroll
      for (int kvs = 0; kvs < 4; ++kvs) {
        unsigned int lo0 = u[4 * kvs + 0], lo1 = u[4 * kvs + 1];  // A: g = 2*kvs
        unsigned int hi0 = u[4 * kvs + 2], hi1 = u[4 * kvs + 3];  // B: g = 2*kvs+1
        asm volatile("v_permlane32_swap_b32 %0, %1" : "+v"(lo0), "+v"(hi0));
        asm volatile("v_permlane32_swap_b32 %0, %1" : "+v"(lo1), "+v"(hi1));
        union { short8 v; unsigned int q[4]; } P;
        P.q[0] = lo0; P.q[1] = lo1; P.q[2] = hi0; P.q[3] = hi1;
        pb[kvs] = P.v;
      }

      // ---- PV: O^T[d][q] += V^T-frag x P-frag ----
      __builtin_amdgcn_s_setprio(1);
#pragma unroll
      for (int dt = 0; dt < 4; ++dt) {
#pragma unroll
        for (int kvs = 0; kvs < 4; ++kvs) {
          short8 av = *(const short8*)(sV + (dt * 32 + lq) * 128 + ((kvs * 32 + hi * 16) ^ swz));
          acc[dt] = MFMA32(av, pb[kvs], acc[dt]);
        }
      }
      __builtin_amdgcn_s_setprio(0);
    }
    __builtin_amdgcn_s_barrier();
  }

  // ---- normalize + LDS transpose + coalesced store ----
  float inv = 1.f / lrow;
  __syncthreads();
  char* myO = lds + w * 8192;            // [32 q][256B d], XOR-swizzled
#pragma unroll
  for (int dt = 0; dt < 4; ++dt)
#pragma unroll
    for (int i = 0; i < 8; ++i) {
      int d = ((2 * i) & 3) + 8 * (i >> 1) + 4 * hi;
      unsigned int pkd = pk2(acc[dt][2 * i] * inv, acc[dt][2 * i + 1] * inv);
      *(unsigned int*)(myO + lq * 256 + ((dt * 64 + d * 2) ^ ((lq & 7) << 4))) = pkd;
    }
  __syncthreads();
  const int row0 = b * T + qt * 256;
#pragma unroll
  for (int p = 0; p < 8; ++p) {
    int off = (p * 512 + tid) * 16;
    int q = off >> 8, cb = off & 255;
    short8 v = *(const short8*)(lds + (q >> 5) * 8192 + (q & 31) * 256 + (cb ^ ((q & 7) << 4)));
    *(short8*)((char*)y + ((size_t)(row0 + q) * 2048 + h * 128) * 2 + cb) = v;
  }
}

// ---------------- launch ----------------
extern "C" void kernel_launch(void* const* d_in, const int* in_sizes, int n_in,
                              void* d_out, int out_size, void* d_ws, size_t ws_size,
                              hipStream_t stream) {
  const float* x    = (const float*)d_in[0];
  const float* cosp = (const float*)d_in[1];
  const float* sinp = (const float*)d_in[2];
  const float* wq   = (const float*)d_in[3];
  const float* wk   = (const float*)d_in[4];
  const float* wv   = (const float*)d_in[5];
  const float* wp   = (const float*)d_in[6];
  float* out = (float*)d_out;

  constexpr size_t Mtok = 8192;  // B*T
  constexpr int Cdim = 2048, HD = 2048, KVD = 512, QKVW = 3072;

  char* ws = (char*)d_ws;
  bf16* xb    = (bf16*)ws; ws += Mtok * Cdim * 2;
  bf16* wqkvT = (bf16*)ws; ws += (size_t)QKVW * Cdim * 2;  // rows: wq^T | wk^T | wv^T
  bf16* wpT   = (bf16*)ws; ws += (size_t)Cdim * HD * 2;
  bf16* qkv   = (bf16*)ws; ws += Mtok * QKVW * 2;
  bf16* vtb   = (bf16*)ws; ws += Mtok * KVD * 2;
  bf16* yb    = (bf16*)ws; ws += Mtok * HD * 2;

  f32_to_bf16_k<<<dim3(Mtok * Cdim / 8 / 256), 256, 0, stream>>>(x, xb, Mtok * Cdim);
  transpose_cvt_k<<<dim3(HD / 32, Cdim / 32), 256, 0, stream>>>(wq, wqkvT, Cdim, HD);
  transpose_cvt_k<<<dim3(KVD / 32, Cdim / 32), 256, 0, stream>>>(wk, wqkvT + (size_t)2048 * Cdim, Cdim, KVD);
  transpose_cvt_k<<<dim3(KVD / 32, Cdim / 32), 256, 0, stream>>>(wv, wqkvT + (size_t)2560 * Cdim, Cdim, KVD);
  transpose_cvt_k<<<dim3(Cdim / 32, HD / 32), 256, 0, stream>>>(wp, wpT, HD, Cdim);

  // fused QKV projection: [8192 x 3072] = xb [8192 x 2048] * wqkvT^T
  gemm256<bf16><<<dim3(384), 512, 0, stream>>>(xb, wqkvT, qkv, (int)Mtok, QKVW, Cdim, 12);

  rope_rms_k<<<dim3(Mtok * 16 / 4), 256, 0, stream>>>(qkv, QKVW, 0, cosp, sinp, 16,
                                                      0.08838834764831845f);
  rope_rms_k<<<dim3(Mtok * 4 / 4), 256, 0, stream>>>(qkv, QKVW, 2048, cosp, sinp, 4, 1.0f);
  transpose_v_k<<<dim3(64, 4, 16), 256, 0, stream>>>(qkv, vtb);

  attn_k<<<dim3(512), 512, 0, stream>>>(qkv, vtb, yb);

  gemm256<float><<<dim3(256), 512, 0, stream>>>(yb, wpT, out, (int)Mtok, HD, Cdim, 8);
}

// Round 7
// 322.634 us; speedup vs baseline: 2.6329x; 1.0609x over previous
//
#include <hip/hip_runtime.h>
#include <hip/hip_bf16.h>
#include <stdint.h>

using bf16 = __hip_bfloat16;
typedef __attribute__((ext_vector_type(8))) short short8;
typedef __attribute__((ext_vector_type(4))) float f32x4;
typedef __attribute__((ext_vector_type(16))) float f32x16;

#define MFMA16(a,b,c) __builtin_amdgcn_mfma_f32_16x16x32_bf16(a,b,c,0,0,0)
#define MFMA32(a,b,c) __builtin_amdgcn_mfma_f32_32x32x16_bf16(a,b,c,0,0,0)

__device__ __forceinline__ void gload_lds16(const void* g, void* l) {
  __builtin_amdgcn_global_load_lds((const __attribute__((address_space(1))) void*)g,
                                   (__attribute__((address_space(3))) void*)l, 16, 0, 0);
}

__device__ __forceinline__ short bf_bits(float f) {
  bf16 h = __float2bfloat16(f);
  return *reinterpret_cast<short*>(&h);
}
__device__ __forceinline__ unsigned int pk2(float a, float b) {
  return ((unsigned int)(unsigned short)bf_bits(b) << 16) | (unsigned short)bf_bits(a);
}
__device__ __forceinline__ float bf2f(short s) {
  return __uint_as_float((unsigned int)(unsigned short)s << 16);
}

// ---------------- f32 -> bf16 elementwise (8/thread) ----------------
__global__ __launch_bounds__(256) void f32_to_bf16_k(const float* __restrict__ in,
                                                     bf16* __restrict__ out, size_t n) {
  size_t i = ((size_t)blockIdx.x * 256 + threadIdx.x) * 8;
  if (i >= n) return;
  float4 a = *(const float4*)(in + i);
  float4 b = *(const float4*)(in + i + 4);
  short8 pk;
  pk[0] = bf_bits(a.x); pk[1] = bf_bits(a.y); pk[2] = bf_bits(a.z); pk[3] = bf_bits(a.w);
  pk[4] = bf_bits(b.x); pk[5] = bf_bits(b.y); pk[6] = bf_bits(b.z); pk[7] = bf_bits(b.w);
  *(short8*)(out + i) = pk;
}

// ---------------- transpose + convert: in[K][N] f32 -> out[N][K] bf16 ----------------
__global__ __launch_bounds__(256) void transpose_cvt_k(const float* __restrict__ in,
                                                       bf16* __restrict__ out, int K, int N) {
  __shared__ float tile[32][33];
  int n0 = blockIdx.x * 32, k0 = blockIdx.y * 32;
  int tx = threadIdx.x & 31, ty = threadIdx.x >> 5;  // 32 x 8
#pragma unroll
  for (int j = 0; j < 4; ++j) {
    int kk = ty + j * 8;
    tile[kk][tx] = in[(size_t)(k0 + kk) * N + n0 + tx];
  }
  __syncthreads();
#pragma unroll
  for (int j = 0; j < 4; ++j) {
    int nn = ty + j * 8;
    out[(size_t)(n0 + nn) * K + k0 + tx] = __float2bfloat16(tile[tx][nn]);
  }
}

// ---------------- V transpose: qkv[(b*T+t)][2560 + kv*128 + d] -> vt[((b*4+kv)*128+d)][t] ----------------
__global__ __launch_bounds__(256) void transpose_v_k(const bf16* __restrict__ qkv,
                                                     bf16* __restrict__ vt) {
  constexpr int T = 2048, Dh = 128, KV = 4, QKVW = 3072, VOFF = 2560;
  __shared__ bf16 tile[32][33];
  int t0 = blockIdx.x * 32, d0 = blockIdx.y * 32;
  int b = blockIdx.z >> 2, kv = blockIdx.z & 3;
  int tx = threadIdx.x & 31, ty = threadIdx.x >> 5;
#pragma unroll
  for (int j = 0; j < 4; ++j) {
    int tt = ty + j * 8;
    tile[tt][tx] = qkv[((size_t)(b * T + t0 + tt)) * QKVW + VOFF + kv * Dh + d0 + tx];
  }
  __syncthreads();
#pragma unroll
  for (int j = 0; j < 4; ++j) {
    int dd = ty + j * 8;
    vt[((size_t)((b * KV + kv) * Dh + d0 + dd)) * T + t0 + tx] = tile[tx][dd];
  }
}

// ---------------- fused RoPE + RMSNorm (in place), 1 wave per (token,head) row ----------------
__global__ __launch_bounds__(256) void rope_rms_k(bf16* __restrict__ buf, int rowstride,
                                                  int baseoff,
                                                  const float* __restrict__ cosp,
                                                  const float* __restrict__ sinp,
                                                  int nh, float outscale) {
  constexpr int T = 2048;
  int wid = blockIdx.x * 4 + (threadIdx.x >> 6);
  int lane = threadIdx.x & 63;
  int h = wid % nh;
  int tok = wid / nh;          // b*T + t
  int t = tok & (T - 1);
  bf16* p = buf + (size_t)tok * rowstride + baseoff + h * 128;
  float x1 = __bfloat162float(p[lane]);
  float x2 = __bfloat162float(p[lane + 64]);
  float c = cosp[t * 64 + lane], s = sinp[t * 64 + lane];
  float o1 = x1 * c - x2 * s;
  float o2 = x1 * s + x2 * c;
  float ss = o1 * o1 + o2 * o2;
#pragma unroll
  for (int m = 1; m < 64; m <<= 1) ss += __shfl_xor(ss, m, 64);
  float r = rsqrtf(ss * (1.f / 128.f) + 1e-5f) * outscale;
  p[lane] = __float2bfloat16(o1 * r);
  p[lane + 64] = __float2bfloat16(o2 * r);
}

// ---------------- 256x256 8-phase bf16 GEMM: C[.][ldC] = A[M][K] * Bt[N][K]^T ----------------
#define PHASE(buf, i0, ...)                                                       \
  {                                                                               \
    short8 a00 = ldA(buf, i0, 0), a01 = ldA(buf, i0, 1);                          \
    short8 a10 = ldA(buf, (i0) + 1, 0), a11 = ldA(buf, (i0) + 1, 1);              \
    __VA_ARGS__;                                                                  \
    __builtin_amdgcn_s_barrier();                                                 \
    asm volatile("s_waitcnt lgkmcnt(0)" ::: "memory");                            \
    __builtin_amdgcn_s_setprio(1);                                                \
    _Pragma("unroll") for (int j = 0; j < 4; ++j) {                               \
      acc[i0][j] = MFMA16(a00, bf_[2 * j], acc[i0][j]);                           \
      acc[i0][j] = MFMA16(a01, bf_[2 * j + 1], acc[i0][j]);                       \
      acc[(i0) + 1][j] = MFMA16(a10, bf_[2 * j], acc[(i0) + 1][j]);               \
      acc[(i0) + 1][j] = MFMA16(a11, bf_[2 * j + 1], acc[(i0) + 1][j]);           \
    }                                                                             \
    __builtin_amdgcn_s_setprio(0);                                                \
  }
#define LOADB(buf)                                                                \
  _Pragma("unroll") for (int j = 0; j < 4; ++j) {                                 \
    bf_[2 * j] = ldB(buf, j, 0);                                                  \
    bf_[2 * j + 1] = ldB(buf, j, 1);                                              \
  }
#define BAR __builtin_amdgcn_s_barrier()

template <typename OutT>
__global__ __launch_bounds__(512, 2) void gemm256(const bf16* __restrict__ A,
                                                  const bf16* __restrict__ Bt,
                                                  OutT* __restrict__ C, int K,
                                                  int NT, int ldC) {
  __shared__ char lds[131072];
  const int tid = threadIdx.x, lane = tid & 63, w = tid >> 6;
  const int wm = w >> 2, wn = w & 3;
  const int bx = blockIdx.x;
  const int chunk = gridDim.x >> 3;
  const int wgid = (bx & 7) * chunk + (bx >> 3);   // XCD-bijective (grid % 8 == 0)
  const int m0 = (wgid / NT) * 256, n0 = (wgid % NT) * 256;
  const int lm = lane & 15;
  const int sw = (lane & 7) << 4;
  const int g16 = (lane >> 4) << 4;
  const size_t strideAB = (size_t)K * 2;  // bytes per row

  auto stageA = [&](int buf, int h, int t) {
#pragma unroll
    for (int p2 = 0; p2 < 2; ++p2) {
      int off = tid * 16 + p2 * 8192;
      int row = off >> 7, cb = off & 127;
      int scb = cb ^ ((row & 7) << 4);
      gload_lds16((const char*)A + (size_t)(m0 + h * 128 + row) * strideAB + t * 128 + scb,
                  lds + buf * 65536 + h * 16384 + off);
    }
  };
  auto stageB = [&](int buf, int h, int t) {
#pragma unroll
    for (int p2 = 0; p2 < 2; ++p2) {
      int off = tid * 16 + p2 * 8192;
      int row = off >> 7, cb = off & 127;
      int scb = cb ^ ((row & 7) << 4);
      gload_lds16((const char*)Bt + (size_t)(n0 + h * 128 + row) * strideAB + t * 128 + scb,
                  lds + buf * 65536 + 32768 + h * 16384 + off);
    }
  };
  auto ldA = [&](int buf, int i, int ks) {
    int row = wm * 128 + i * 16 + lm;
    return *(const short8*)(lds + buf * 65536 + row * 128 + ((ks * 64 + g16) ^ sw));
  };
  auto ldB = [&](int buf, int j, int ks) {
    int row = wn * 64 + j * 16 + lm;
    return *(const short8*)(lds + buf * 65536 + 32768 + row * 128 + ((ks * 64 + g16) ^ sw));
  };

  f32x4 acc[8][4] = {};
  short8 bf_[8];
  const int niter = K / 128;

  stageA(0, 0, 0); stageA(0, 1, 0); stageB(0, 0, 0); stageB(0, 1, 0);
  stageB(1, 0, 1); stageB(1, 1, 1);
  asm volatile("s_waitcnt vmcnt(4)" ::: "memory");
  BAR;

  for (int i = 0; i < niter; ++i) {
    const int t0 = 2 * i, t1 = 2 * i + 1;
    const bool nl = (i + 1 < niter);
    LOADB(0);
    PHASE(0, 0, stageA(1, 0, t1)); BAR;
    PHASE(0, 2, stageA(1, 1, t1)); BAR;
    PHASE(0, 4, if (nl) stageB(0, 0, t0 + 2)); BAR;
    PHASE(0, 6, if (nl) stageB(0, 1, t0 + 2));
    if (nl) { asm volatile("s_waitcnt vmcnt(4)" ::: "memory"); }
    else    { asm volatile("s_waitcnt vmcnt(0)" ::: "memory"); }
    BAR;
    LOADB(1);
    PHASE(1, 0, if (nl) stageA(0, 0, t0 + 2)); BAR;
    PHASE(1, 2, if (nl) stageA(0, 1, t0 + 2)); BAR;
    PHASE(1, 4, if (nl) stageB(1, 0, t1 + 2)); BAR;
    PHASE(1, 6, if (nl) stageB(1, 1, t1 + 2));
    if (nl) { asm volatile("s_waitcnt vmcnt(4)" ::: "memory"); }
    BAR;
  }

  if constexpr (sizeof(OutT) == 2) {
    __syncthreads();
    bf16* sC = (bf16*)lds;
#pragma unroll
    for (int i = 0; i < 8; ++i) {
      int row = wm * 128 + i * 16 + (lane >> 4) * 4;
#pragma unroll
      for (int j = 0; j < 4; ++j) {
        int col = wn * 64 + j * 16 + lm;
#pragma unroll
        for (int r = 0; r < 4; ++r) sC[(row + r) * 256 + col] = __float2bfloat16(acc[i][j][r]);
      }
    }
    __syncthreads();
#pragma unroll
    for (int p = 0; p < 16; ++p) {
      int off = tid * 16 + p * 8192;
      int row = off >> 9, cb = off & 511;
      *(short8*)((char*)C + ((size_t)(m0 + row) * ldC + n0) * 2 + cb) =
          *(const short8*)(lds + off);
    }
  } else {
#pragma unroll
    for (int i = 0; i < 8; ++i) {
      int row = m0 + wm * 128 + i * 16 + (lane >> 4) * 4;
#pragma unroll
      for (int j = 0; j < 4; ++j) {
        int col = n0 + wn * 64 + j * 16 + lm;
#pragma unroll
        for (int r = 0; r < 4; ++r) C[(size_t)(row + r) * ldC + col] = acc[i][j][r];
      }
    }
  }
}

// ---------------- 128x128 bf16 GEMM (m97 structure) for the small KV projection ----------------
template <typename OutT>
__global__ __launch_bounds__(256) void gemm_bt(const bf16* __restrict__ A,
                                               const bf16* __restrict__ Bt,
                                               OutT* __restrict__ C, int K,
                                               int NT, int ldC) {
  constexpr int BM = 128, BN = 128, BK = 64;
  __shared__ char smem[32768];
  bf16* sA = (bf16*)smem;
  bf16* sB = (bf16*)(smem + 16384);
  int tid = threadIdx.x;
  int lane = tid & 63, w = tid >> 6;
  int flat = blockIdx.x;
  int wgid = (flat & 7) * (gridDim.x >> 3) + (flat >> 3);
  int m0 = (wgid / NT) * BM, n0 = (wgid % NT) * BN;
  int wm = (w >> 1) * 64, wn = (w & 1) * 64;
  f32x4 acc[4][4] = {};
  int nk = K / BK;
  for (int kt = 0; kt < nk; ++kt) {
    __syncthreads();
    int kb = kt * BK;
#pragma unroll
    for (int it = 0; it < 4; ++it) {
      int off = tid * 16 + it * 4096;
      int row = off >> 7, cb = off & 127;
      gload_lds16((const char*)A + (((size_t)(m0 + row)) * K + kb) * 2 + cb, (char*)sA + off);
    }
#pragma unroll
    for (int it = 0; it < 4; ++it) {
      int off = tid * 16 + it * 4096;
      int row = off >> 7, cb = off & 127;
      gload_lds16((const char*)Bt + (((size_t)(n0 + row)) * K + kb) * 2 + cb, (char*)sB + off);
    }
    asm volatile("s_waitcnt vmcnt(0)" ::: "memory");
    __syncthreads();
#pragma unroll
    for (int ks = 0; ks < 2; ++ks) {
      short8 af[4], bfr[4];
#pragma unroll
      for (int i = 0; i < 4; ++i) {
        af[i]  = *(const short8*)(sA + (wm + i * 16 + (lane & 15)) * BK + ks * 32 + (lane >> 4) * 8);
        bfr[i] = *(const short8*)(sB + (wn + i * 16 + (lane & 15)) * BK + ks * 32 + (lane >> 4) * 8);
      }
#pragma unroll
      for (int i = 0; i < 4; ++i)
#pragma unroll
        for (int j = 0; j < 4; ++j)
          acc[i][j] = MFMA16(af[i], bfr[j], acc[i][j]);
    }
  }
  if constexpr (sizeof(OutT) == 2) {
    __syncthreads();
    bf16* sC = (bf16*)smem;
#pragma unroll
    for (int i = 0; i < 4; ++i) {
      int row = wm + i * 16 + (lane >> 4) * 4;
#pragma unroll
      for (int j = 0; j < 4; ++j) {
        int col = wn + j * 16 + (lane & 15);
#pragma unroll
        for (int r = 0; r < 4; ++r)
          sC[(row + r) * BN + col] = __float2bfloat16(acc[i][j][r]);
      }
    }
    __syncthreads();
#pragma unroll
    for (int it = 0; it < 8; ++it) {
      int off = tid * 16 + it * 4096;
      int row = off >> 8, cb = off & 255;
      *(short8*)((char*)C + ((size_t)(m0 + row) * ldC + n0) * 2 + cb) =
          *(const short8*)(smem + off);
    }
  } else {
#pragma unroll
    for (int i = 0; i < 4; ++i) {
      int row = m0 + wm + i * 16 + (lane >> 4) * 4;
#pragma unroll
      for (int j = 0; j < 4; ++j) {
        int col = n0 + wn + j * 16 + (lane & 15);
#pragma unroll
        for (int r = 0; r < 4; ++r)
          C[(size_t)(row + r) * ldC + col] = acc[i][j][r];
      }
    }
  }
}

// ---------------- flash attention: 8-wave 32x32 swapped-QK^T + fused Q-RoPE/RMS ----------------
// qkv[(b*T+t)][3072]: q RAW at h*128, k (roped+rms'd) at 2048+kh*128. vt[((b*4+kv)*128+d)][t]
__global__ __launch_bounds__(512, 2) void attn_k(const bf16* __restrict__ qkv,
                                                 const bf16* __restrict__ vt,
                                                 bf16* __restrict__ y,
                                                 const float* __restrict__ cosp,
                                                 const float* __restrict__ sinp) {
  constexpr int T = 2048, Dh = 128, KV = 4, KB = 64, QKVW = 3072, KOFF = 2048;
  __shared__ char lds[65536];
  const int tid = threadIdx.x, lane = tid & 63, w = tid >> 6;
  const int hi = lane >> 5, lq = lane & 31;
  const int bx = blockIdx.x;
  const int qt = 7 - (bx >> 6);          // longest blocks dispatch first
  const int b = (bx >> 4) & 3, h = bx & 15;
  const int kh = h >> 2;
  const int q0 = qt * 256 + w * 32;
  const int qg = q0 + lq;
  const int swz = (lane & 7) << 4;

  // Q fragments (B-operand): aq[m] = Q[qg][m*16 + hi*8 .. +8]
  short8 aq[8];
  {
    const bf16* qp = qkv + ((size_t)(b * T + qg)) * QKVW + h * Dh + hi * 8;
#pragma unroll
    for (int m = 0; m < 8; ++m) aq[m] = *(const short8*)(qp + m * 16);
  }
  __builtin_amdgcn_s_waitcnt(0);

  // ---- fused RoPE + RMS on Q (rotation preserves row norm -> rms from raw q).
  // rope pair (d, d+64) = (aq[m][e], aq[m+4][e]) with d = m*16+hi*8+e: lane-local.
  {
    float ss = 0.f;
#pragma unroll
    for (int m = 0; m < 8; ++m)
#pragma unroll
      for (int e = 0; e < 8; ++e) { float v = bf2f(aq[m][e]); ss += v * v; }
    ss += __shfl_xor(ss, 32, 64);
    float rn = rsqrtf(ss * (1.f / 128.f) + 1e-5f) * 0.08838834764831845f;
    const float4* cq4 = (const float4*)(cosp + (size_t)qg * 64) + hi * 2;
    const float4* sq4 = (const float4*)(sinp + (size_t)qg * 64) + hi * 2;
#pragma unroll
    for (int m = 0; m < 4; ++m) {
      float4 c0 = cq4[m * 4], c1 = cq4[m * 4 + 1];
      float4 s0 = sq4[m * 4], s1 = sq4[m * 4 + 1];
      float cc[8] = {c0.x, c0.y, c0.z, c0.w, c1.x, c1.y, c1.z, c1.w};
      float sn[8] = {s0.x, s0.y, s0.z, s0.w, s1.x, s1.y, s1.z, s1.w};
      short8 xl = aq[m], xh = aq[m + 4], nl, nh;
#pragma unroll
      for (int e = 0; e < 8; ++e) {
        float x1 = bf2f(xl[e]), x2 = bf2f(xh[e]);
        nl[e] = bf_bits((x1 * cc[e] - x2 * sn[e]) * rn);
        nh[e] = bf_bits((x1 * sn[e] + x2 * cc[e]) * rn);
      }
      aq[m] = nl; aq[m + 4] = nh;
    }
  }

  f32x16 acc[4] = {};
  float mrow = -1e4f, lrow = 0.f;

  auto stage = [&](int buf, int kv0) {
#pragma unroll
    for (int p = 0; p < 2; ++p) {        // K: [64 kv][256B]
      int off = tid * 16 + p * 8192;
      int row = off >> 8, cb = off & 255;
      int scb = cb ^ ((row & 7) << 4);
      gload_lds16((const char*)qkv + (((size_t)(b * T + kv0 + row)) * QKVW + KOFF + kh * Dh) * 2 + scb,
                  lds + buf * 16384 + off);
    }
#pragma unroll
    for (int p = 0; p < 2; ++p) {        // V^T: [128 d][128B]
      int off = tid * 16 + p * 8192;
      int row = off >> 7, cb = off & 127;
      int scb = cb ^ ((row & 7) << 4);
      gload_lds16((const char*)vt + (((size_t)((b * KV + kh) * Dh + row)) * T + kv0) * 2 + scb,
                  lds + 32768 + buf * 16384 + off);
    }
  };

  const int nt = (qt + 1) * 4;
  const int lastit = (q0 + 31) >> 6;
  stage(0, 0);

  for (int it = 0; it < nt; ++it) {
    int cur = it & 1;
    if (it + 1 < nt) { stage(cur ^ 1, (it + 1) * KB); asm volatile("s_waitcnt vmcnt(4)" ::: "memory"); }
    else             { asm volatile("s_waitcnt vmcnt(0)" ::: "memory"); }
    __builtin_amdgcn_s_barrier();
    if (it <= lastit) {
      const char* sK = lds + cur * 16384;
      const char* sV = lds + 32768 + cur * 16384;
      const int kv0 = it * KB;

      // ---- QK^T: S^T[kv][q], A=K (rows kv), B=Q (cols q) ----
      f32x16 s0 = {}, s1 = {};
      __builtin_amdgcn_s_setprio(1);
#pragma unroll
      for (int m = 0; m < 8; ++m) {
        short8 ak = *(const short8*)(sK + lq * 256 + ((m * 32 + hi * 16) ^ swz));
        s0 = MFMA32(ak, aq[m], s0);
      }
#pragma unroll
      for (int m = 0; m < 8; ++m) {
        short8 ak = *(const short8*)(sK + (32 + lq) * 256 + ((m * 32 + hi * 16) ^ swz));
        s1 = MFMA32(ak, aq[m], s1);
      }
      __builtin_amdgcn_s_setprio(0);

      // ---- causal mask ----
      if (kv0 + 63 > q0) {
#pragma unroll
        for (int r = 0; r < 16; ++r) {
          int krow = (r & 3) + 8 * (r >> 2) + 4 * hi;
          if (kv0 + krow > qg) s0[r] = -1e30f;
          if (kv0 + 32 + krow > qg) s1[r] = -1e30f;
        }
      }

      // ---- online softmax, in-register ----
      float tmax = s0[0];
#pragma unroll
      for (int r = 1; r < 16; ++r) tmax = fmaxf(tmax, s0[r]);
#pragma unroll
      for (int r = 0; r < 16; ++r) tmax = fmaxf(tmax, s1[r]);
      tmax = fmaxf(tmax, __shfl_xor(tmax, 32, 64));
      if (!__all(tmax - mrow <= 8.0f)) {   // defer-max (T13)
        float mn = fmaxf(mrow, tmax);
        float corr = __expf(mrow - mn);
        mrow = mn;
        lrow *= corr;
#pragma unroll
        for (int dt = 0; dt < 4; ++dt)
#pragma unroll
          for (int r = 0; r < 16; ++r) acc[dt][r] *= corr;
      }
      float rsum = 0.f;
#pragma unroll
      for (int r = 0; r < 16; ++r) { s0[r] = __expf(s0[r] - mrow); rsum += s0[r]; }
#pragma unroll
      for (int r = 0; r < 16; ++r) { s1[r] = __expf(s1[r] - mrow); rsum += s1[r]; }
      rsum += __shfl_xor(rsum, 32, 64);
      lrow += rsum;

      // ---- P -> bf16 B-fragments: 16 packs + 8 permlane32_swap (vdst = low-g word) ----
      unsigned int u[16];
#pragma unroll
      for (int g = 0; g < 4; ++g) {
        u[g * 2 + 0] = pk2(s0[4 * g + 0], s0[4 * g + 1]);
        u[g * 2 + 1] = pk2(s0[4 * g + 2], s0[4 * g + 3]);
        u[8 + g * 2 + 0] = pk2(s1[4 * g + 0], s1[4 * g + 1]);
        u[8 + g * 2 + 1] = pk2(s1[4 * g + 2], s1[4 * g + 3]);
      }
      short8 pb[4];
#pragma unroll
      for (int kvs = 0; kvs < 4; ++kvs) {
        unsigned int lo0 = u[4 * kvs + 0], lo1 = u[4 * kvs + 1];
        unsigned int hi0 = u[4 * kvs + 2], hi1 = u[4 * kvs + 3];
        asm volatile("v_permlane32_swap_b32 %0, %1" : "+v"(lo0), "+v"(hi0));
        asm volatile("v_permlane32_swap_b32 %0, %1" : "+v"(lo1), "+v"(hi1));
        union { short8 v; unsigned int q[4]; } P;
        P.q[0] = lo0; P.q[1] = lo1; P.q[2] = hi0; P.q[3] = hi1;
        pb[kvs] = P.v;
      }

      // ---- PV: O^T[d][q] += V^T-frag x P-frag ----
      __builtin_amdgcn_s_setprio(1);
#pragma unroll
      for (int dt = 0; dt < 4; ++dt) {
#pragma unroll
        for (int kvs = 0; kvs < 4; ++kvs) {
          short8 av = *(const short8*)(sV + (dt * 32 + lq) * 128 + ((kvs * 32 + hi * 16) ^ swz));
          acc[dt] = MFMA32(av, pb[kvs], acc[dt]);
        }
      }
      __builtin_amdgcn_s_setprio(0);
    }
    __builtin_amdgcn_s_barrier();
  }

  // ---- normalize + LDS transpose + coalesced store ----
  float inv = 1.f / lrow;
  __syncthreads();
  char* myO = lds + w * 8192;
#pragma unroll
  for (int dt = 0; dt < 4; ++dt)
#pragma unroll
    for (int i = 0; i < 8; ++i) {
      int d = ((2 * i) & 3) + 8 * (i >> 1) + 4 * hi;
      unsigned int pkd = pk2(acc[dt][2 * i] * inv, acc[dt][2 * i + 1] * inv);
      *(unsigned int*)(myO + lq * 256 + ((dt * 64 + d * 2) ^ ((lq & 7) << 4))) = pkd;
    }
  __syncthreads();
  const int row0 = b * T + qt * 256;
#pragma unroll
  for (int p = 0; p < 8; ++p) {
    int off = (p * 512 + tid) * 16;
    int q = off >> 8, cb = off & 255;
    short8 v = *(const short8*)(lds + (q >> 5) * 8192 + (q & 31) * 256 + (cb ^ ((q & 7) << 4)));
    *(short8*)((char*)y + ((size_t)(row0 + q) * 2048 + h * 128) * 2 + cb) = v;
  }
}

// ---------------- launch ----------------
extern "C" void kernel_launch(void* const* d_in, const int* in_sizes, int n_in,
                              void* d_out, int out_size, void* d_ws, size_t ws_size,
                              hipStream_t stream) {
  const float* x    = (const float*)d_in[0];
  const float* cosp = (const float*)d_in[1];
  const float* sinp = (const float*)d_in[2];
  const float* wq   = (const float*)d_in[3];
  const float* wk   = (const float*)d_in[4];
  const float* wv   = (const float*)d_in[5];
  const float* wp   = (const float*)d_in[6];
  float* out = (float*)d_out;

  constexpr size_t Mtok = 8192;  // B*T
  constexpr int Cdim = 2048, HD = 2048, KVD = 512, QKVW = 3072;

  char* ws = (char*)d_ws;
  bf16* xb    = (bf16*)ws; ws += Mtok * Cdim * 2;
  bf16* wqkvT = (bf16*)ws; ws += (size_t)QKVW * Cdim * 2;  // rows: wq^T | wk^T | wv^T
  bf16* wpT   = (bf16*)ws; ws += (size_t)Cdim * HD * 2;
  bf16* qkv   = (bf16*)ws; ws += Mtok * QKVW * 2;
  bf16* vtb   = (bf16*)ws; ws += Mtok * KVD * 2;
  bf16* yb    = (bf16*)ws; ws += Mtok * HD * 2;

  f32_to_bf16_k<<<dim3(Mtok * Cdim / 8 / 256), 256, 0, stream>>>(x, xb, Mtok * Cdim);
  transpose_cvt_k<<<dim3(HD / 32, Cdim / 32), 256, 0, stream>>>(wq, wqkvT, Cdim, HD);
  transpose_cvt_k<<<dim3(KVD / 32, Cdim / 32), 256, 0, stream>>>(wk, wqkvT + (size_t)2048 * Cdim, Cdim, KVD);
  transpose_cvt_k<<<dim3(KVD / 32, Cdim / 32), 256, 0, stream>>>(wv, wqkvT + (size_t)2560 * Cdim, Cdim, KVD);
  transpose_cvt_k<<<dim3(Cdim / 32, HD / 32), 256, 0, stream>>>(wp, wpT, HD, Cdim);

  // Q projection: 256 tiles = exact 1-round packing
  gemm256<bf16><<<dim3(256), 512, 0, stream>>>(xb, wqkvT, qkv, Cdim, 8, QKVW);
  // KV projection: small (34 GF) -> 128^2 kernel, 512 WGs all-resident
  gemm_bt<bf16><<<dim3(512), 256, 0, stream>>>(xb, wqkvT + (size_t)2048 * Cdim,
                                               (bf16*)qkv + 2048, Cdim, 8, QKVW);

  rope_rms_k<<<dim3(Mtok * 4 / 4), 256, 0, stream>>>(qkv, QKVW, 2048, cosp, sinp, 4, 1.0f);
  transpose_v_k<<<dim3(64, 4, 16), 256, 0, stream>>>(qkv, vtb);

  attn_k<<<dim3(512), 512, 0, stream>>>(qkv, vtb, yb, cosp, sinp);

  gemm256<float><<<dim3(256), 512, 0, stream>>>(yb, wpT, out, Cdim, 8, 2048);
}